// Round 1
// baseline (270.295 us; speedup 1.0000x reference)
//
#include <hip/hip_runtime.h>

typedef _Float16 f16;
typedef _Float16 f16x8 __attribute__((ext_vector_type(8)));
typedef _Float16 f16x4 __attribute__((ext_vector_type(4)));
typedef float f32x4 __attribute__((ext_vector_type(4)));

#define MFMA16(a, b, c) __builtin_amdgcn_mfma_f32_16x16x32_f16(a, b, c, 0, 0, 0)

// ---------------- weight packing ----------------
// Packed B-panel layout per weight: panels over (kb, nb); each panel = 512 f16:
//   element ((kb*(N/16)+nb)*64 + lane)*8 + i  holds  B[k][n],
//   k = kb*32 + (lane>>4)*8 + i,  n = nb*16 + (lane&15)
//   B[k][n] = transpose ? W[n*K+k] : W[k*N+n]
__device__ __forceinline__ void pack_one(int local, const float* __restrict__ src,
                                         f16* __restrict__ dst, int K, int N, int transpose) {
    int i = local & 7;
    int l = (local >> 3) & 63;
    int p = local >> 9;
    int nt16 = N >> 4;
    int nb = p % nt16;
    int kb = p / nt16;
    int k = kb * 32 + ((l >> 4) << 3) + i;
    int n = nb * 16 + (l & 15);
    float v = transpose ? src[n * K + k] : src[k * N + n];
    dst[local] = (f16)v;
}

__global__ void pack_weights(const float* __restrict__ w00, const float* __restrict__ w01,
                             const float* __restrict__ w10, const float* __restrict__ w110,
                             const float* __restrict__ w111, const float* __restrict__ W0e,
                             const float* __restrict__ W1o, const float* __restrict__ W1e,
                             f16* __restrict__ dst) {
    int idx = blockIdx.x * 256 + threadIdx.x;
    if (idx < 65536)        pack_one(idx,          w00,  dst,          256, 256, 1);
    else if (idx < 98304)   pack_one(idx - 65536,  w01,  dst + 65536,  128, 256, 1);
    else if (idx < 131072)  pack_one(idx - 98304,  w10,  dst + 98304,  256, 128, 1);
    else if (idx < 147456)  pack_one(idx - 131072, w110, dst + 131072, 128, 128, 1);
    else if (idx < 163840)  pack_one(idx - 147456, w111, dst + 147456, 128, 128, 1);
    else if (idx < 262144)  pack_one(idx - 163840, W0e,  dst + 163840, 384, 256, 0);
    else if (idx < 311296)  pack_one(idx - 262144, W1o,  dst + 262144, 384, 128, 0);
    else                    pack_one(idx - 311296, W1e,  dst + 311296, 128, 128, 0);
}

// ---------------- main fused kernel ----------------
// NT=32: LDS footprint 72 KiB -> 2 blocks/CU (was NT=64 / 144 KiB / 1 block/CU).
#define NT 32
// LDS map (byte offsets)
#define S16B   0                        // [32][256] f16, pitch 512B (16 KiB)
#define VBASE(j) (16384 + (j) * 8192)   // [32][128] f16, pitch 256B (3 x 8 KiB)
#define TB     40960                    // [32][384] f16, pitch 768B (24 KiB)
#define A3B    65536                    // [32][128] f16, pitch 256B (8 KiB)
#define MBASE(j) (TB + (j) * 8192)      // reuse T as three [32][128] planes
#define P5BASE(j) ((j) == 0 ? A3B : (S16B + ((j) - 1) * 8192))
#define LDS_BYTES 73728

__device__ __forceinline__ f16x8 afrag(const unsigned char* lds, int base, int pitchh,
                                       int row0, int k0, int lr, int lg) {
    int row = row0 + lr;
    int off = base + row * (pitchh * 2) + (((k0 + (lg << 3)) * 2) ^ ((row & 7) << 4));
    return *(const f16x8*)(lds + off);
}
__device__ __forceinline__ float ldsf(const unsigned char* lds, int base, int pitchh,
                                      int row, int col) {
    int off = base + row * (pitchh * 2) + ((col * 2) ^ ((row & 7) << 4));
    return (float)*(const f16*)(lds + off);
}
__device__ __forceinline__ void ldss(unsigned char* lds, int base, int pitchh,
                                     int row, int col, float v) {
    int off = base + row * (pitchh * 2) + ((col * 2) ^ ((row & 7) << 4));
    *(f16*)(lds + off) = (f16)v;
}
__device__ __forceinline__ f16x8 bfrag(const f16* __restrict__ panel, int nt16, int kb,
                                       int nb, int lane) {
    return *(const f16x8*)(panel + (size_t)((kb * nt16 + nb) * 512 + lane * 8));
}

__global__ __launch_bounds__(512, 4)
void node_tp(const float* __restrict__ nf, const f16* __restrict__ wp,
             float* __restrict__ out, int n_nodes) {
    __shared__ __align__(16) unsigned char lds[LDS_BYTES];
    const int tid = threadIdx.x;
    const int lane = tid & 63;
    const int wv = tid >> 6;
    const int z0 = blockIdx.x * NT;
    const int nvalid = min(NT, n_nodes - z0);
    const int lr = lane & 15;
    const int lg = lane >> 4;

    const f16* w00p  = wp;
    const f16* w01p  = wp + 65536;
    const f16* w10p  = wp + 98304;
    const f16* w110p = wp + 131072;
    const f16* w111p = wp + 147456;
    const f16* W0ep  = wp + 163840;
    const f16* W1op  = wp + 262144;
    const f16* W1ep  = wp + 311296;

    const float C000 = 0.0625f;               // 1/sqrt(256)
    const float C011 = 0.08838834764831843f;  // 1/sqrt(128)
    const float C101 = 0.0625f;
    const float C110 = 0.05103103630798287f;  // 1/sqrt(384)
    const float C111 = 0.0625f;               // 1/16
    const float RS384 = 0.05103103630798287f;
    const float RS128 = 0.08838834764831843f;

    // ---- P0: stage node_feat -> LDS f16 (swizzled) ----
    for (int q = tid; q < NT * 160; q += 512) {
        int row = q / 160;
        int c4 = q - row * 160;
        float4 v4 = make_float4(0.f, 0.f, 0.f, 0.f);
        if (row < nvalid)
            v4 = ((const float4*)(nf + (size_t)(z0 + row) * 640))[c4];
        int c = c4 * 4;
        if (c < 256) {
            f16x4 h = {(f16)v4.x, (f16)v4.y, (f16)v4.z, (f16)v4.w};
            int off = S16B + row * 512 + ((c * 2) ^ ((row & 7) << 4));
            *(f16x4*)(lds + off) = h;
        } else {
            float vv[4] = {v4.x, v4.y, v4.z, v4.w};
            for (int e = 0; e < 4; ++e) {
                int m = c - 256 + e;
                int u = m / 3;
                int j = m - u * 3;
                ldss(lds, VBASE(j), 128, row, u, vv[e]);
            }
        }
    }
    __syncthreads();

    // ---- P1: A1 = S @ w00^T ; p1 = C000*S*A1 -> T[:,0:256] ----
    {
        f32x4 acc[2][2] = {};
        for (int ks = 0; ks < 8; ++ks) {
            f16x8 b0 = bfrag(w00p, 16, ks, 2 * wv, lane);
            f16x8 b1 = bfrag(w00p, 16, ks, 2 * wv + 1, lane);
            for (int mt = 0; mt < 2; ++mt) {
                f16x8 a = afrag(lds, S16B, 256, mt * 16, ks * 32, lr, lg);
                acc[mt][0] = MFMA16(a, b0, acc[mt][0]);
                acc[mt][1] = MFMA16(a, b1, acc[mt][1]);
            }
        }
        for (int mt = 0; mt < 2; ++mt)
            for (int nn = 0; nn < 2; ++nn) {
                int u = (2 * wv + nn) * 16 + lr;
                for (int r = 0; r < 4; ++r) {
                    int z = mt * 16 + lg * 4 + r;
                    float s = ldsf(lds, S16B, 256, z, u);
                    ldss(lds, TB, 384, z, u, C000 * s * acc[mt][nn][r]);
                }
            }
    }
    // ---- P2: A4j = Vj @ w11_0^T ; p4 = C110*sum_j Vj*A4j -> T[:,256:384] ----
    {
        f32x4 acc[2][3] = {};
        for (int ks = 0; ks < 4; ++ks) {
            f16x8 b = bfrag(w110p, 8, ks, wv, lane);
            for (int j = 0; j < 3; ++j)
                for (int mt = 0; mt < 2; ++mt) {
                    f16x8 a = afrag(lds, VBASE(j), 128, mt * 16, ks * 32, lr, lg);
                    acc[mt][j] = MFMA16(a, b, acc[mt][j]);
                }
        }
        for (int mt = 0; mt < 2; ++mt) {
            int u = wv * 16 + lr;
            for (int r = 0; r < 4; ++r) {
                int z = mt * 16 + lg * 4 + r;
                float p4 = 0.f;
                for (int j = 0; j < 3; ++j)
                    p4 += ldsf(lds, VBASE(j), 128, z, u) * acc[mt][j][r];
                ldss(lds, TB, 384, z, 256 + u, C110 * p4);
            }
        }
    }
    __syncthreads();

    // ---- P3: out_0e = T @ W0e / sqrt(384) ----
    {
        f32x4 acc[2][2] = {};
        for (int ks = 0; ks < 12; ++ks) {
            f16x8 b0 = bfrag(W0ep, 16, ks, 2 * wv, lane);
            f16x8 b1 = bfrag(W0ep, 16, ks, 2 * wv + 1, lane);
            for (int mt = 0; mt < 2; ++mt) {
                f16x8 a = afrag(lds, TB, 384, mt * 16, ks * 32, lr, lg);
                acc[mt][0] = MFMA16(a, b0, acc[mt][0]);
                acc[mt][1] = MFMA16(a, b1, acc[mt][1]);
            }
        }
        for (int mt = 0; mt < 2; ++mt)
            for (int nn = 0; nn < 2; ++nn) {
                int u = (2 * wv + nn) * 16 + lr;
                for (int r = 0; r < 4; ++r) {
                    int z = mt * 16 + lg * 4 + r;
                    if (z < nvalid)
                        out[(size_t)(z0 + z) * 1024 + u] = RS384 * acc[mt][nn][r];
                }
            }
    }
    // ---- P4: A3 = S @ w10^T -> A3B (raw) ----
    {
        f32x4 acc[2] = {};
        for (int ks = 0; ks < 8; ++ks) {
            f16x8 b = bfrag(w10p, 8, ks, wv, lane);
            for (int mt = 0; mt < 2; ++mt) {
                f16x8 a = afrag(lds, S16B, 256, mt * 16, ks * 32, lr, lg);
                acc[mt] = MFMA16(a, b, acc[mt]);
            }
        }
        for (int mt = 0; mt < 2; ++mt) {
            int u = wv * 16 + lr;
            for (int r = 0; r < 4; ++r) {
                int z = mt * 16 + lg * 4 + r;
                ldss(lds, A3B, 128, z, u, acc[mt][r]);
            }
        }
    }
    __syncthreads();

    // ---- P5: for j: {A2j -> p2 -> T[:,0:256]; p3 -> T[:,256:384]; out1o_j += T@W1o} ----
    f32x4 acc1o[2][3] = {};
    for (int j = 0; j < 3; ++j) {
        {
            f32x4 a2[2][2] = {};
            for (int ks = 0; ks < 4; ++ks) {
                f16x8 b0 = bfrag(w01p, 16, ks, 2 * wv, lane);
                f16x8 b1 = bfrag(w01p, 16, ks, 2 * wv + 1, lane);
                for (int mt = 0; mt < 2; ++mt) {
                    f16x8 a = afrag(lds, VBASE(j), 128, mt * 16, ks * 32, lr, lg);
                    a2[mt][0] = MFMA16(a, b0, a2[mt][0]);
                    a2[mt][1] = MFMA16(a, b1, a2[mt][1]);
                }
            }
            for (int mt = 0; mt < 2; ++mt)
                for (int nn = 0; nn < 2; ++nn) {
                    int u = (2 * wv + nn) * 16 + lr;
                    for (int r = 0; r < 4; ++r) {
                        int z = mt * 16 + lg * 4 + r;
                        float s = ldsf(lds, S16B, 256, z, u);
                        ldss(lds, TB, 384, z, u, C011 * s * a2[mt][nn][r]);
                    }
                }
        }
        for (int q = tid; q < NT * 128; q += 512) {
            int z = q >> 7, u = q & 127;
            float vv = ldsf(lds, VBASE(j), 128, z, u);
            float a3 = ldsf(lds, A3B, 128, z, u);
            ldss(lds, TB, 384, z, 256 + u, C101 * vv * a3);
        }
        __syncthreads();
        for (int ks = 0; ks < 12; ++ks) {
            f16x8 b = bfrag(W1op, 8, ks, wv, lane);
            for (int mt = 0; mt < 2; ++mt) {
                f16x8 a = afrag(lds, TB, 384, mt * 16, ks * 32, lr, lg);
                acc1o[mt][j] = MFMA16(a, b, acc1o[mt][j]);
            }
        }
        __syncthreads();
    }
    for (int mt = 0; mt < 2; ++mt) {
        int o = wv * 16 + lr;
        for (int r = 0; r < 4; ++r) {
            int z = mt * 16 + lg * 4 + r;
            if (z < nvalid) {
                size_t base = (size_t)(z0 + z) * 1024 + 256 + 3 * o;
                out[base + 0] = RS384 * acc1o[mt][0][r];
                out[base + 1] = RS384 * acc1o[mt][1][r];
                out[base + 2] = RS384 * acc1o[mt][2][r];
            }
        }
    }

    // ---- P6: Mj = Vj @ w11_1^T -> T planes; cross -> p5 planes ----
    for (int j = 0; j < 3; ++j) {
        f32x4 am[2] = {};
        for (int ks = 0; ks < 4; ++ks) {
            f16x8 b = bfrag(w111p, 8, ks, wv, lane);
            for (int mt = 0; mt < 2; ++mt) {
                f16x8 a = afrag(lds, VBASE(j), 128, mt * 16, ks * 32, lr, lg);
                am[mt] = MFMA16(a, b, am[mt]);
            }
        }
        for (int mt = 0; mt < 2; ++mt) {
            int u = wv * 16 + lr;
            for (int r = 0; r < 4; ++r) {
                int z = mt * 16 + lg * 4 + r;
                ldss(lds, MBASE(j), 128, z, u, am[mt][r]);
            }
        }
    }
    __syncthreads();
    for (int q = tid; q < NT * 128; q += 512) {
        int z = q >> 7, u = q & 127;
        float v0 = ldsf(lds, VBASE(0), 128, z, u);
        float v1 = ldsf(lds, VBASE(1), 128, z, u);
        float v2 = ldsf(lds, VBASE(2), 128, z, u);
        float m0 = ldsf(lds, MBASE(0), 128, z, u);
        float m1 = ldsf(lds, MBASE(1), 128, z, u);
        float m2 = ldsf(lds, MBASE(2), 128, z, u);
        ldss(lds, P5BASE(0), 128, z, u, C111 * (v1 * m2 - v2 * m1));
        ldss(lds, P5BASE(1), 128, z, u, C111 * (v2 * m0 - v0 * m2));
        ldss(lds, P5BASE(2), 128, z, u, C111 * (v0 * m1 - v1 * m0));
    }
    __syncthreads();

    // ---- P7: out_1e_j = p5_j @ W1e / sqrt(128) ----
    {
        f32x4 acc[2][3] = {};
        for (int j = 0; j < 3; ++j)
            for (int ks = 0; ks < 4; ++ks) {
                f16x8 b = bfrag(W1ep, 8, ks, wv, lane);
                for (int mt = 0; mt < 2; ++mt) {
                    f16x8 a = afrag(lds, P5BASE(j), 128, mt * 16, ks * 32, lr, lg);
                    acc[mt][j] = MFMA16(a, b, acc[mt][j]);
                }
            }
        for (int mt = 0; mt < 2; ++mt) {
            int o = wv * 16 + lr;
            for (int r = 0; r < 4; ++r) {
                int z = mt * 16 + lg * 4 + r;
                if (z < nvalid) {
                    size_t base = (size_t)(z0 + z) * 1024 + 640 + 3 * o;
                    out[base + 0] = RS128 * acc[mt][0][r];
                    out[base + 1] = RS128 * acc[mt][1][r];
                    out[base + 2] = RS128 * acc[mt][2][r];
                }
            }
        }
    }
}

extern "C" void kernel_launch(void* const* d_in, const int* in_sizes, int n_in,
                              void* d_out, int out_size, void* d_ws, size_t ws_size,
                              hipStream_t stream) {
    const float* nf   = (const float*)d_in[0];
    const float* w00  = (const float*)d_in[1];
    const float* w01  = (const float*)d_in[2];
    const float* w10  = (const float*)d_in[3];
    const float* w110 = (const float*)d_in[4];
    const float* w111 = (const float*)d_in[5];
    const float* W0e  = (const float*)d_in[6];
    const float* W1o  = (const float*)d_in[7];
    const float* W1e  = (const float*)d_in[8];
    f16* wpack = (f16*)d_ws;  // needs 655,360 bytes

    int n_nodes = in_sizes[0] / 640;
    pack_weights<<<1280, 256, 0, stream>>>(w00, w01, w10, w110, w111, W0e, W1o, W1e, wpack);
    int blocks = (n_nodes + NT - 1) / NT;
    node_tp<<<blocks, 512, 0, stream>>>(nf, wpack, (float*)d_out, n_nodes);
}

// Round 2
// 257.870 us; speedup vs baseline: 1.0482x; 1.0482x over previous
//
#include <hip/hip_runtime.h>

typedef _Float16 f16;
typedef _Float16 f16x8 __attribute__((ext_vector_type(8)));
typedef _Float16 f16x4 __attribute__((ext_vector_type(4)));
typedef float f32x4 __attribute__((ext_vector_type(4)));

#define MFMA16(a, b, c) __builtin_amdgcn_mfma_f32_16x16x32_f16(a, b, c, 0, 0, 0)

// ---------------- weight packing ----------------
// Packed B-panel layout per weight: panels over (kb, nb); each panel = 512 f16:
//   element ((kb*(N/16)+nb)*64 + lane)*8 + i  holds  B[k][n],
//   k = kb*32 + (lane>>4)*8 + i,  n = nb*16 + (lane&15)
//   B[k][n] = transpose ? W[n*K+k] : W[k*N+n]
__device__ __forceinline__ void pack_one(int local, const float* __restrict__ src,
                                         f16* __restrict__ dst, int K, int N, int transpose) {
    int i = local & 7;
    int l = (local >> 3) & 63;
    int p = local >> 9;
    int nt16 = N >> 4;
    int nb = p % nt16;
    int kb = p / nt16;
    int k = kb * 32 + ((l >> 4) << 3) + i;
    int n = nb * 16 + (l & 15);
    float v = transpose ? src[n * K + k] : src[k * N + n];
    dst[local] = (f16)v;
}

__global__ void pack_weights(const float* __restrict__ w00, const float* __restrict__ w01,
                             const float* __restrict__ w10, const float* __restrict__ w110,
                             const float* __restrict__ w111, const float* __restrict__ W0e,
                             const float* __restrict__ W1o, const float* __restrict__ W1e,
                             f16* __restrict__ dst) {
    int idx = blockIdx.x * 256 + threadIdx.x;
    if (idx < 65536)        pack_one(idx,          w00,  dst,          256, 256, 1);
    else if (idx < 98304)   pack_one(idx - 65536,  w01,  dst + 65536,  128, 256, 1);
    else if (idx < 131072)  pack_one(idx - 98304,  w10,  dst + 98304,  256, 128, 1);
    else if (idx < 147456)  pack_one(idx - 131072, w110, dst + 131072, 128, 128, 1);
    else if (idx < 163840)  pack_one(idx - 147456, w111, dst + 147456, 128, 128, 1);
    else if (idx < 262144)  pack_one(idx - 163840, W0e,  dst + 163840, 384, 256, 0);
    else if (idx < 311296)  pack_one(idx - 262144, W1o,  dst + 262144, 384, 128, 0);
    else                    pack_one(idx - 311296, W1e,  dst + 311296, 128, 128, 0);
}

// ---------------- main fused kernel ----------------
// NT=64 (known-good traffic profile). ks loops ROLLED (#pragma unroll 1) with a
// 1-deep manual B-panel double-buffer: shrinks code ~5-10x to fit the 32 KiB I$.
#define NT 64
// LDS map (byte offsets)
#define S16B   0                        // [64][256] f16, pitch 512B
#define VBASE(j) (32768 + (j) * 16384)  // [64][128] f16, pitch 256B
#define TB     81920                    // [64][384] f16, pitch 768B
#define A3B    131072                   // [64][128] f16, pitch 256B
#define MBASE(j) (TB + (j) * 16384)     // reuse T as three [64][128] planes
#define P5BASE(j) ((j) == 0 ? A3B : (S16B + ((j) - 1) * 16384))
#define LDS_BYTES 147456

__device__ __forceinline__ f16x8 afrag(const unsigned char* lds, int base, int pitchh,
                                       int row0, int k0, int lr, int lg) {
    int row = row0 + lr;
    int off = base + row * (pitchh * 2) + (((k0 + (lg << 3)) * 2) ^ ((row & 7) << 4));
    return *(const f16x8*)(lds + off);
}
__device__ __forceinline__ float ldsf(const unsigned char* lds, int base, int pitchh,
                                      int row, int col) {
    int off = base + row * (pitchh * 2) + ((col * 2) ^ ((row & 7) << 4));
    return (float)*(const f16*)(lds + off);
}
__device__ __forceinline__ void ldss(unsigned char* lds, int base, int pitchh,
                                     int row, int col, float v) {
    int off = base + row * (pitchh * 2) + ((col * 2) ^ ((row & 7) << 4));
    *(f16*)(lds + off) = (f16)v;
}
__device__ __forceinline__ f16x8 bfrag(const f16* __restrict__ panel, int nt16, int kb,
                                       int nb, int lane) {
    return *(const f16x8*)(panel + (size_t)((kb * nt16 + nb) * 512 + lane * 8));
}

__global__ __launch_bounds__(512, 2)
void node_tp(const float* __restrict__ nf, const f16* __restrict__ wp,
             float* __restrict__ out, int n_nodes) {
    __shared__ __align__(16) unsigned char lds[LDS_BYTES];
    const int tid = threadIdx.x;
    const int lane = tid & 63;
    const int wv = tid >> 6;
    const int z0 = blockIdx.x * NT;
    const int nvalid = min(NT, n_nodes - z0);
    const int lr = lane & 15;
    const int lg = lane >> 4;

    const f16* w00p  = wp;
    const f16* w01p  = wp + 65536;
    const f16* w10p  = wp + 98304;
    const f16* w110p = wp + 131072;
    const f16* w111p = wp + 147456;
    const f16* W0ep  = wp + 163840;
    const f16* W1op  = wp + 262144;
    const f16* W1ep  = wp + 311296;

    const float C000 = 0.0625f;               // 1/sqrt(256)
    const float C011 = 0.08838834764831843f;  // 1/sqrt(128)
    const float C101 = 0.0625f;
    const float C110 = 0.05103103630798287f;  // 1/sqrt(384)
    const float C111 = 0.0625f;               // 1/16
    const float RS384 = 0.05103103630798287f;
    const float RS128 = 0.08838834764831843f;

    // ---- P0: stage node_feat -> LDS f16 (swizzled) ----
    #pragma unroll 1
    for (int q = tid; q < NT * 160; q += 512) {
        int row = q / 160;
        int c4 = q - row * 160;
        float4 v4 = make_float4(0.f, 0.f, 0.f, 0.f);
        if (row < nvalid)
            v4 = ((const float4*)(nf + (size_t)(z0 + row) * 640))[c4];
        int c = c4 * 4;
        if (c < 256) {
            f16x4 h = {(f16)v4.x, (f16)v4.y, (f16)v4.z, (f16)v4.w};
            int off = S16B + row * 512 + ((c * 2) ^ ((row & 7) << 4));
            *(f16x4*)(lds + off) = h;
        } else {
            float vv[4] = {v4.x, v4.y, v4.z, v4.w};
            #pragma unroll
            for (int e = 0; e < 4; ++e) {
                int m = c - 256 + e;
                int u = m / 3;
                int j = m - u * 3;
                ldss(lds, VBASE(j), 128, row, u, vv[e]);
            }
        }
    }
    __syncthreads();

    // ---- P1: A1 = S @ w00^T ; p1 = C000*S*A1 -> T[:,0:256] ----
    {
        f32x4 acc[4][2] = {};
        f16x8 b0 = bfrag(w00p, 16, 0, 2 * wv, lane);
        f16x8 b1 = bfrag(w00p, 16, 0, 2 * wv + 1, lane);
        #pragma unroll 1
        for (int ks = 0; ks < 8; ++ks) {
            int kn = ks + 1 < 8 ? ks + 1 : ks;
            f16x8 c0 = bfrag(w00p, 16, kn, 2 * wv, lane);
            f16x8 c1 = bfrag(w00p, 16, kn, 2 * wv + 1, lane);
            #pragma unroll
            for (int mt = 0; mt < 4; ++mt) {
                f16x8 a = afrag(lds, S16B, 256, mt * 16, ks * 32, lr, lg);
                acc[mt][0] = MFMA16(a, b0, acc[mt][0]);
                acc[mt][1] = MFMA16(a, b1, acc[mt][1]);
            }
            b0 = c0; b1 = c1;
        }
        #pragma unroll
        for (int mt = 0; mt < 4; ++mt)
            #pragma unroll
            for (int nn = 0; nn < 2; ++nn) {
                int u = (2 * wv + nn) * 16 + lr;
                #pragma unroll
                for (int r = 0; r < 4; ++r) {
                    int z = mt * 16 + lg * 4 + r;
                    float s = ldsf(lds, S16B, 256, z, u);
                    ldss(lds, TB, 384, z, u, C000 * s * acc[mt][nn][r]);
                }
            }
    }
    // ---- P2: A4j = Vj @ w11_0^T ; p4 = C110*sum_j Vj*A4j -> T[:,256:384] ----
    {
        f32x4 acc[4][3] = {};
        f16x8 b = bfrag(w110p, 8, 0, wv, lane);
        #pragma unroll 1
        for (int ks = 0; ks < 4; ++ks) {
            int kn = ks + 1 < 4 ? ks + 1 : ks;
            f16x8 c = bfrag(w110p, 8, kn, wv, lane);
            #pragma unroll
            for (int j = 0; j < 3; ++j)
                #pragma unroll
                for (int mt = 0; mt < 4; ++mt) {
                    f16x8 a = afrag(lds, VBASE(j), 128, mt * 16, ks * 32, lr, lg);
                    acc[mt][j] = MFMA16(a, b, acc[mt][j]);
                }
            b = c;
        }
        #pragma unroll
        for (int mt = 0; mt < 4; ++mt) {
            int u = wv * 16 + lr;
            #pragma unroll
            for (int r = 0; r < 4; ++r) {
                int z = mt * 16 + lg * 4 + r;
                float p4 = 0.f;
                #pragma unroll
                for (int j = 0; j < 3; ++j)
                    p4 += ldsf(lds, VBASE(j), 128, z, u) * acc[mt][j][r];
                ldss(lds, TB, 384, z, 256 + u, C110 * p4);
            }
        }
    }
    __syncthreads();

    // ---- P3: out_0e = T @ W0e / sqrt(384) ----
    {
        f32x4 acc[4][2] = {};
        f16x8 b0 = bfrag(W0ep, 16, 0, 2 * wv, lane);
        f16x8 b1 = bfrag(W0ep, 16, 0, 2 * wv + 1, lane);
        #pragma unroll 1
        for (int ks = 0; ks < 12; ++ks) {
            int kn = ks + 1 < 12 ? ks + 1 : ks;
            f16x8 c0 = bfrag(W0ep, 16, kn, 2 * wv, lane);
            f16x8 c1 = bfrag(W0ep, 16, kn, 2 * wv + 1, lane);
            #pragma unroll
            for (int mt = 0; mt < 4; ++mt) {
                f16x8 a = afrag(lds, TB, 384, mt * 16, ks * 32, lr, lg);
                acc[mt][0] = MFMA16(a, b0, acc[mt][0]);
                acc[mt][1] = MFMA16(a, b1, acc[mt][1]);
            }
            b0 = c0; b1 = c1;
        }
        #pragma unroll
        for (int mt = 0; mt < 4; ++mt)
            #pragma unroll
            for (int nn = 0; nn < 2; ++nn) {
                int u = (2 * wv + nn) * 16 + lr;
                #pragma unroll
                for (int r = 0; r < 4; ++r) {
                    int z = mt * 16 + lg * 4 + r;
                    if (z < nvalid)
                        out[(size_t)(z0 + z) * 1024 + u] = RS384 * acc[mt][nn][r];
                }
            }
    }
    // ---- P4: A3 = S @ w10^T -> A3B (raw) ----
    {
        f32x4 acc[4] = {};
        f16x8 b = bfrag(w10p, 8, 0, wv, lane);
        #pragma unroll 1
        for (int ks = 0; ks < 8; ++ks) {
            int kn = ks + 1 < 8 ? ks + 1 : ks;
            f16x8 c = bfrag(w10p, 8, kn, wv, lane);
            #pragma unroll
            for (int mt = 0; mt < 4; ++mt) {
                f16x8 a = afrag(lds, S16B, 256, mt * 16, ks * 32, lr, lg);
                acc[mt] = MFMA16(a, b, acc[mt]);
            }
            b = c;
        }
        #pragma unroll
        for (int mt = 0; mt < 4; ++mt) {
            int u = wv * 16 + lr;
            #pragma unroll
            for (int r = 0; r < 4; ++r) {
                int z = mt * 16 + lg * 4 + r;
                ldss(lds, A3B, 128, z, u, acc[mt][r]);
            }
        }
    }
    __syncthreads();

    // ---- P5: for j: {A2j -> p2 -> T[:,0:256]; p3 -> T[:,256:384]; out1o_j += T@W1o} ----
    f32x4 acc1o[4][3] = {};
    #pragma unroll
    for (int j = 0; j < 3; ++j) {
        {
            f32x4 a2[4][2] = {};
            f16x8 b0 = bfrag(w01p, 16, 0, 2 * wv, lane);
            f16x8 b1 = bfrag(w01p, 16, 0, 2 * wv + 1, lane);
            #pragma unroll 1
            for (int ks = 0; ks < 4; ++ks) {
                int kn = ks + 1 < 4 ? ks + 1 : ks;
                f16x8 c0 = bfrag(w01p, 16, kn, 2 * wv, lane);
                f16x8 c1 = bfrag(w01p, 16, kn, 2 * wv + 1, lane);
                #pragma unroll
                for (int mt = 0; mt < 4; ++mt) {
                    f16x8 a = afrag(lds, VBASE(j), 128, mt * 16, ks * 32, lr, lg);
                    a2[mt][0] = MFMA16(a, b0, a2[mt][0]);
                    a2[mt][1] = MFMA16(a, b1, a2[mt][1]);
                }
                b0 = c0; b1 = c1;
            }
            #pragma unroll
            for (int mt = 0; mt < 4; ++mt)
                #pragma unroll
                for (int nn = 0; nn < 2; ++nn) {
                    int u = (2 * wv + nn) * 16 + lr;
                    #pragma unroll
                    for (int r = 0; r < 4; ++r) {
                        int z = mt * 16 + lg * 4 + r;
                        float s = ldsf(lds, S16B, 256, z, u);
                        ldss(lds, TB, 384, z, u, C011 * s * a2[mt][nn][r]);
                    }
                }
        }
        #pragma unroll 1
        for (int q = tid; q < NT * 128; q += 512) {
            int z = q >> 7, u = q & 127;
            float vv = ldsf(lds, VBASE(j), 128, z, u);
            float a3 = ldsf(lds, A3B, 128, z, u);
            ldss(lds, TB, 384, z, 256 + u, C101 * vv * a3);
        }
        __syncthreads();
        {
            f16x8 b = bfrag(W1op, 8, 0, wv, lane);
            #pragma unroll 1
            for (int ks = 0; ks < 12; ++ks) {
                int kn = ks + 1 < 12 ? ks + 1 : ks;
                f16x8 c = bfrag(W1op, 8, kn, wv, lane);
                #pragma unroll
                for (int mt = 0; mt < 4; ++mt) {
                    f16x8 a = afrag(lds, TB, 384, mt * 16, ks * 32, lr, lg);
                    acc1o[mt][j] = MFMA16(a, b, acc1o[mt][j]);
                }
                b = c;
            }
        }
        __syncthreads();
    }
    #pragma unroll
    for (int mt = 0; mt < 4; ++mt) {
        int o = wv * 16 + lr;
        #pragma unroll
        for (int r = 0; r < 4; ++r) {
            int z = mt * 16 + lg * 4 + r;
            if (z < nvalid) {
                size_t base = (size_t)(z0 + z) * 1024 + 256 + 3 * o;
                out[base + 0] = RS384 * acc1o[mt][0][r];
                out[base + 1] = RS384 * acc1o[mt][1][r];
                out[base + 2] = RS384 * acc1o[mt][2][r];
            }
        }
    }

    // ---- P6: Mj = Vj @ w11_1^T -> T planes; cross -> p5 planes ----
    #pragma unroll 1
    for (int j = 0; j < 3; ++j) {
        f32x4 am[4] = {};
        f16x8 b = bfrag(w111p, 8, 0, wv, lane);
        #pragma unroll 1
        for (int ks = 0; ks < 4; ++ks) {
            int kn = ks + 1 < 4 ? ks + 1 : ks;
            f16x8 c = bfrag(w111p, 8, kn, wv, lane);
            #pragma unroll
            for (int mt = 0; mt < 4; ++mt) {
                f16x8 a = afrag(lds, VBASE(j), 128, mt * 16, ks * 32, lr, lg);
                am[mt] = MFMA16(a, b, am[mt]);
            }
            b = c;
        }
        #pragma unroll
        for (int mt = 0; mt < 4; ++mt) {
            int u = wv * 16 + lr;
            #pragma unroll
            for (int r = 0; r < 4; ++r) {
                int z = mt * 16 + lg * 4 + r;
                ldss(lds, MBASE(j), 128, z, u, am[mt][r]);
            }
        }
    }
    __syncthreads();
    #pragma unroll 1
    for (int q = tid; q < NT * 128; q += 512) {
        int z = q >> 7, u = q & 127;
        float v0 = ldsf(lds, VBASE(0), 128, z, u);
        float v1 = ldsf(lds, VBASE(1), 128, z, u);
        float v2 = ldsf(lds, VBASE(2), 128, z, u);
        float m0 = ldsf(lds, MBASE(0), 128, z, u);
        float m1 = ldsf(lds, MBASE(1), 128, z, u);
        float m2 = ldsf(lds, MBASE(2), 128, z, u);
        ldss(lds, P5BASE(0), 128, z, u, C111 * (v1 * m2 - v2 * m1));
        ldss(lds, P5BASE(1), 128, z, u, C111 * (v2 * m0 - v0 * m2));
        ldss(lds, P5BASE(2), 128, z, u, C111 * (v0 * m1 - v1 * m0));
    }
    __syncthreads();

    // ---- P7: out_1e_j = p5_j @ W1e / sqrt(128) ----
    {
        f32x4 acc[4][3] = {};
        #pragma unroll
        for (int j = 0; j < 3; ++j) {
            f16x8 b = bfrag(W1ep, 8, 0, wv, lane);
            #pragma unroll 1
            for (int ks = 0; ks < 4; ++ks) {
                int kn = ks + 1 < 4 ? ks + 1 : ks;
                f16x8 c = bfrag(W1ep, 8, kn, wv, lane);
                #pragma unroll
                for (int mt = 0; mt < 4; ++mt) {
                    f16x8 a = afrag(lds, P5BASE(j), 128, mt * 16, ks * 32, lr, lg);
                    acc[mt][j] = MFMA16(a, b, acc[mt][j]);
                }
                b = c;
            }
        }
        #pragma unroll
        for (int mt = 0; mt < 4; ++mt) {
            int o = wv * 16 + lr;
            #pragma unroll
            for (int r = 0; r < 4; ++r) {
                int z = mt * 16 + lg * 4 + r;
                if (z < nvalid) {
                    size_t base = (size_t)(z0 + z) * 1024 + 640 + 3 * o;
                    out[base + 0] = RS128 * acc[mt][0][r];
                    out[base + 1] = RS128 * acc[mt][1][r];
                    out[base + 2] = RS128 * acc[mt][2][r];
                }
            }
        }
    }
}

extern "C" void kernel_launch(void* const* d_in, const int* in_sizes, int n_in,
                              void* d_out, int out_size, void* d_ws, size_t ws_size,
                              hipStream_t stream) {
    const float* nf   = (const float*)d_in[0];
    const float* w00  = (const float*)d_in[1];
    const float* w01  = (const float*)d_in[2];
    const float* w10  = (const float*)d_in[3];
    const float* w110 = (const float*)d_in[4];
    const float* w111 = (const float*)d_in[5];
    const float* W0e  = (const float*)d_in[6];
    const float* W1o  = (const float*)d_in[7];
    const float* W1e  = (const float*)d_in[8];
    f16* wpack = (f16*)d_ws;  // needs 655,360 bytes

    int n_nodes = in_sizes[0] / 640;
    pack_weights<<<1280, 256, 0, stream>>>(w00, w01, w10, w110, w111, W0e, W1o, W1e, wpack);
    int blocks = (n_nodes + NT - 1) / NT;
    node_tp<<<blocks, 512, 0, stream>>>(nf, wpack, (float*)d_out, n_nodes);
}

// Round 3
// 237.175 us; speedup vs baseline: 1.1396x; 1.0873x over previous
//
#include <hip/hip_runtime.h>

typedef _Float16 f16;
typedef _Float16 f16x8 __attribute__((ext_vector_type(8)));
typedef _Float16 f16x4 __attribute__((ext_vector_type(4)));
typedef float f32x4 __attribute__((ext_vector_type(4)));

#define MFMA16(a, b, c) __builtin_amdgcn_mfma_f32_16x16x32_f16(a, b, c, 0, 0, 0)

// ---------------- weight packing (A-operand layout) ----------------
// Panels over (kb, rb); each panel = 512 f16:
//   element ((kb*(R/16)+rb)*64 + lane)*8 + i  holds  A[r][k],
//   r = rb*16 + (lane&15),  k = kb*32 + (lane>>4)*8 + i
//   A[r][k] = transpose ? W[k*R+r] : W[r*K+k]
__device__ __forceinline__ void pack_one(int local, const float* __restrict__ src,
                                         f16* __restrict__ dst, int K, int R, int transpose) {
    int i = local & 7;
    int l = (local >> 3) & 63;
    int p = local >> 9;
    int rt16 = R >> 4;
    int rb = p % rt16;
    int kb = p / rt16;
    int k = kb * 32 + ((l >> 4) << 3) + i;
    int r = rb * 16 + (l & 15);
    float v = transpose ? src[k * R + r] : src[r * K + k];
    dst[local] = (f16)v;
}

__global__ void pack_weights(const float* __restrict__ w00, const float* __restrict__ w01,
                             const float* __restrict__ w10, const float* __restrict__ w110,
                             const float* __restrict__ w111, const float* __restrict__ W0e,
                             const float* __restrict__ W1o, const float* __restrict__ W1e,
                             f16* __restrict__ dst) {
    int idx = blockIdx.x * 256 + threadIdx.x;
    // rows R = output channel dim, K = contraction dim
    if (idx < 65536)        pack_one(idx,          w00,  dst,          256, 256, 0); // A1: A[u][v]=w00[u][v]
    else if (idx < 98304)   pack_one(idx - 65536,  w01,  dst + 65536,  128, 256, 0); // A2: w01[u][v]
    else if (idx < 131072)  pack_one(idx - 98304,  w10,  dst + 98304,  256, 128, 0); // A3: w10[u][v]
    else if (idx < 147456)  pack_one(idx - 131072, w110, dst + 131072, 128, 128, 0); // A4: w110[u][v]
    else if (idx < 163840)  pack_one(idx - 147456, w111, dst + 147456, 128, 128, 0); // M : w111[u][v]
    else if (idx < 262144)  pack_one(idx - 163840, W0e,  dst + 163840, 384, 256, 1); // A[o][t]=W0e[t][o]
    else if (idx < 311296)  pack_one(idx - 262144, W1o,  dst + 262144, 384, 128, 1); // A[o][t]=W1o[t][o]
    else                    pack_one(idx - 311296, W1e,  dst + 311296, 128, 128, 1); // A[o][t]=W1e[t][o]
}

// ---------------- main fused kernel ----------------
// Transposed orientation: C[channel][node]. Weights = A-operand (global),
// node tiles = B-operand (LDS, same swizzled layout as before).
// Epilogues become per-lane contiguous b64 LDS ops (4x fewer instrs).
#define NT 64
// LDS map (byte offsets)
#define S16B   0                        // [64][256] f16, pitch 512B
#define VBASE(j) (32768 + (j) * 16384)  // [64][128] f16, pitch 256B
#define TB     81920                    // [64][384] f16, pitch 768B
#define A3B    131072                   // [64][128] f16, pitch 256B
#define MBASE(j) (TB + (j) * 16384)     // reuse T as three [64][128] planes
#define P5BASE(j) ((j) == 0 ? A3B : (S16B + ((j) - 1) * 16384))
#define LDS_BYTES 147456

// B-operand fragment: lane holds data[row0+lr][k0 + lg*8 .. +7]  (= B[k][n], n=lr)
__device__ __forceinline__ f16x8 afrag(const unsigned char* lds, int base, int pitchh,
                                       int row0, int k0, int lr, int lg) {
    int row = row0 + lr;
    int off = base + row * (pitchh * 2) + (((k0 + (lg << 3)) * 2) ^ ((row & 7) << 4));
    return *(const f16x8*)(lds + off);
}
// vector (4 x f16, 8B) LDS access at (row, col), col % 4 == 0
__device__ __forceinline__ f16x4 ldsv4(const unsigned char* lds, int base, int pitchh,
                                       int row, int col) {
    int off = base + row * (pitchh * 2) + ((col * 2) ^ ((row & 7) << 4));
    return *(const f16x4*)(lds + off);
}
__device__ __forceinline__ void stsv4(unsigned char* lds, int base, int pitchh,
                                      int row, int col, f16x4 v) {
    int off = base + row * (pitchh * 2) + ((col * 2) ^ ((row & 7) << 4));
    *(f16x4*)(lds + off) = v;
}
// scalar store (P0 staging only)
__device__ __forceinline__ void ldss(unsigned char* lds, int base, int pitchh,
                                     int row, int col, float v) {
    int off = base + row * (pitchh * 2) + ((col * 2) ^ ((row & 7) << 4));
    *(f16*)(lds + off) = (f16)v;
}
// weight A-fragment from packed panel
__device__ __forceinline__ f16x8 wfrag(const f16* __restrict__ panel, int rt16, int kb,
                                       int rb, int lane) {
    return *(const f16x8*)(panel + (size_t)((kb * rt16 + rb) * 512 + lane * 8));
}

__global__ __launch_bounds__(512, 2)
void node_tp(const float* __restrict__ nf, const f16* __restrict__ wp,
             float* __restrict__ out, int n_nodes) {
    __shared__ __align__(16) unsigned char lds[LDS_BYTES];
    const int tid = threadIdx.x;
    const int lane = tid & 63;
    const int wv = tid >> 6;
    const int z0 = blockIdx.x * NT;
    const int nvalid = min(NT, n_nodes - z0);
    const int lr = lane & 15;
    const int lg = lane >> 4;

    const f16* w00p  = wp;
    const f16* w01p  = wp + 65536;
    const f16* w10p  = wp + 98304;
    const f16* w110p = wp + 131072;
    const f16* w111p = wp + 147456;
    const f16* W0ep  = wp + 163840;
    const f16* W1op  = wp + 262144;
    const f16* W1ep  = wp + 311296;

    const float C000 = 0.0625f;               // 1/sqrt(256)
    const float C011 = 0.08838834764831843f;  // 1/sqrt(128)
    const float C101 = 0.0625f;
    const float C110 = 0.05103103630798287f;  // 1/sqrt(384)
    const float C111 = 0.0625f;               // 1/16
    const float RS384 = 0.05103103630798287f;
    const float RS128 = 0.08838834764831843f;

    // ---- P0: stage node_feat -> LDS f16 (swizzled, [node][channel]) ----
    #pragma unroll 1
    for (int q = tid; q < NT * 160; q += 512) {
        int row = q / 160;
        int c4 = q - row * 160;
        float4 v4 = make_float4(0.f, 0.f, 0.f, 0.f);
        if (row < nvalid)
            v4 = ((const float4*)(nf + (size_t)(z0 + row) * 640))[c4];
        int c = c4 * 4;
        if (c < 256) {
            f16x4 h = {(f16)v4.x, (f16)v4.y, (f16)v4.z, (f16)v4.w};
            int off = S16B + row * 512 + ((c * 2) ^ ((row & 7) << 4));
            *(f16x4*)(lds + off) = h;
        } else {
            float vv[4] = {v4.x, v4.y, v4.z, v4.w};
            #pragma unroll
            for (int e = 0; e < 4; ++e) {
                int m = c - 256 + e;
                int u = m / 3;
                int j = m - u * 3;
                ldss(lds, VBASE(j), 128, row, u, vv[e]);
            }
        }
    }
    __syncthreads();

    // ---- P1: A1^T tiles = w00 @ S^T ; p1 = C000*S*A1 -> T[:,0:256] ----
    {
        f32x4 acc[2][4] = {};
        f16x8 a0 = wfrag(w00p, 16, 0, 2 * wv, lane);
        f16x8 a1 = wfrag(w00p, 16, 0, 2 * wv + 1, lane);
        #pragma unroll 1
        for (int ks = 0; ks < 8; ++ks) {
            int kn = ks + 1 < 8 ? ks + 1 : ks;
            f16x8 n0 = wfrag(w00p, 16, kn, 2 * wv, lane);
            f16x8 n1 = wfrag(w00p, 16, kn, 2 * wv + 1, lane);
            #pragma unroll
            for (int nt = 0; nt < 4; ++nt) {
                f16x8 b = afrag(lds, S16B, 256, nt * 16, ks * 32, lr, lg);
                acc[0][nt] = MFMA16(a0, b, acc[0][nt]);
                acc[1][nt] = MFMA16(a1, b, acc[1][nt]);
            }
            a0 = n0; a1 = n1;
        }
        #pragma unroll
        for (int rt = 0; rt < 2; ++rt)
            #pragma unroll
            for (int nt = 0; nt < 4; ++nt) {
                int node = nt * 16 + lr;
                int u0 = wv * 32 + rt * 16 + lg * 4;
                f16x4 s4 = ldsv4(lds, S16B, 256, node, u0);
                f16x4 t4;
                #pragma unroll
                for (int r = 0; r < 4; ++r)
                    t4[r] = (f16)(C000 * (float)s4[r] * acc[rt][nt][r]);
                stsv4(lds, TB, 384, node, u0, t4);
            }
    }
    // ---- P2: A4j^T = w110 @ Vj^T ; p4 = C110*sum_j Vj*A4j -> T[:,256:384] ----
    {
        f32x4 acc[3][4] = {};
        #pragma unroll
        for (int ks = 0; ks < 4; ++ks) {
            f16x8 a = wfrag(w110p, 8, ks, wv, lane);
            #pragma unroll
            for (int j = 0; j < 3; ++j)
                #pragma unroll
                for (int nt = 0; nt < 4; ++nt) {
                    f16x8 b = afrag(lds, VBASE(j), 128, nt * 16, ks * 32, lr, lg);
                    acc[j][nt] = MFMA16(a, b, acc[j][nt]);
                }
        }
        #pragma unroll
        for (int nt = 0; nt < 4; ++nt) {
            int node = nt * 16 + lr;
            int u0 = wv * 16 + lg * 4;
            float p4[4] = {0.f, 0.f, 0.f, 0.f};
            #pragma unroll
            for (int j = 0; j < 3; ++j) {
                f16x4 v4 = ldsv4(lds, VBASE(j), 128, node, u0);
                #pragma unroll
                for (int r = 0; r < 4; ++r)
                    p4[r] += (float)v4[r] * acc[j][nt][r];
            }
            f16x4 t4;
            #pragma unroll
            for (int r = 0; r < 4; ++r) t4[r] = (f16)(C110 * p4[r]);
            stsv4(lds, TB, 384, node, 256 + u0, t4);
        }
    }
    __syncthreads();

    // ---- P3: out_0e^T = W0e^T @ T^T / sqrt(384) ----
    {
        f32x4 acc[2][4] = {};
        f16x8 a0 = wfrag(W0ep, 16, 0, 2 * wv, lane);
        f16x8 a1 = wfrag(W0ep, 16, 0, 2 * wv + 1, lane);
        #pragma unroll 1
        for (int ks = 0; ks < 12; ++ks) {
            int kn = ks + 1 < 12 ? ks + 1 : ks;
            f16x8 n0 = wfrag(W0ep, 16, kn, 2 * wv, lane);
            f16x8 n1 = wfrag(W0ep, 16, kn, 2 * wv + 1, lane);
            #pragma unroll
            for (int nt = 0; nt < 4; ++nt) {
                f16x8 b = afrag(lds, TB, 384, nt * 16, ks * 32, lr, lg);
                acc[0][nt] = MFMA16(a0, b, acc[0][nt]);
                acc[1][nt] = MFMA16(a1, b, acc[1][nt]);
            }
            a0 = n0; a1 = n1;
        }
        #pragma unroll
        for (int rt = 0; rt < 2; ++rt)
            #pragma unroll
            for (int nt = 0; nt < 4; ++nt) {
                int node = nt * 16 + lr;
                if (node < nvalid) {
                    int o = wv * 32 + rt * 16 + lg * 4;
                    float4 o4;
                    o4.x = RS384 * acc[rt][nt][0];
                    o4.y = RS384 * acc[rt][nt][1];
                    o4.z = RS384 * acc[rt][nt][2];
                    o4.w = RS384 * acc[rt][nt][3];
                    *(float4*)(&out[(size_t)(z0 + node) * 1024 + o]) = o4;
                }
            }
    }
    // ---- P4: A3^T = w10 @ S^T -> A3B (raw) ----
    {
        f32x4 acc[4] = {};
        f16x8 a = wfrag(w10p, 8, 0, wv, lane);
        #pragma unroll 1
        for (int ks = 0; ks < 8; ++ks) {
            int kn = ks + 1 < 8 ? ks + 1 : ks;
            f16x8 nx = wfrag(w10p, 8, kn, wv, lane);
            #pragma unroll
            for (int nt = 0; nt < 4; ++nt) {
                f16x8 b = afrag(lds, S16B, 256, nt * 16, ks * 32, lr, lg);
                acc[nt] = MFMA16(a, b, acc[nt]);
            }
            a = nx;
        }
        #pragma unroll
        for (int nt = 0; nt < 4; ++nt) {
            int node = nt * 16 + lr;
            f16x4 t4;
            #pragma unroll
            for (int r = 0; r < 4; ++r) t4[r] = (f16)acc[nt][r];
            stsv4(lds, A3B, 128, node, wv * 16 + lg * 4, t4);
        }
    }
    __syncthreads();

    // ---- P5: for j: {A2j -> p2 -> T[:,0:256]; p3 -> T[:,256:384]; out1o_j += W1o^T@T^T} ----
    f32x4 acc1o[4][3] = {};
    #pragma unroll
    for (int j = 0; j < 3; ++j) {
        {
            f32x4 a2[2][4] = {};
            #pragma unroll
            for (int ks = 0; ks < 4; ++ks) {
                f16x8 a0 = wfrag(w01p, 16, ks, 2 * wv, lane);
                f16x8 a1 = wfrag(w01p, 16, ks, 2 * wv + 1, lane);
                #pragma unroll
                for (int nt = 0; nt < 4; ++nt) {
                    f16x8 b = afrag(lds, VBASE(j), 128, nt * 16, ks * 32, lr, lg);
                    a2[0][nt] = MFMA16(a0, b, a2[0][nt]);
                    a2[1][nt] = MFMA16(a1, b, a2[1][nt]);
                }
            }
            #pragma unroll
            for (int rt = 0; rt < 2; ++rt)
                #pragma unroll
                for (int nt = 0; nt < 4; ++nt) {
                    int node = nt * 16 + lr;
                    int u0 = wv * 32 + rt * 16 + lg * 4;
                    f16x4 s4 = ldsv4(lds, S16B, 256, node, u0);
                    f16x4 t4;
                    #pragma unroll
                    for (int r = 0; r < 4; ++r)
                        t4[r] = (f16)(C011 * (float)s4[r] * a2[rt][nt][r]);
                    stsv4(lds, TB, 384, node, u0, t4);
                }
        }
        #pragma unroll 1
        for (int q = tid; q < NT * 32; q += 512) {
            int row = q >> 5;
            int col = (q & 31) * 4;
            f16x4 v4 = ldsv4(lds, VBASE(j), 128, row, col);
            f16x4 a34 = ldsv4(lds, A3B, 128, row, col);
            f16x4 t4;
            #pragma unroll
            for (int r = 0; r < 4; ++r)
                t4[r] = (f16)(C101 * (float)v4[r] * (float)a34[r]);
            stsv4(lds, TB, 384, row, 256 + col, t4);
        }
        __syncthreads();
        {
            f16x8 a = wfrag(W1op, 8, 0, wv, lane);
            #pragma unroll 1
            for (int ks = 0; ks < 12; ++ks) {
                int kn = ks + 1 < 12 ? ks + 1 : ks;
                f16x8 nx = wfrag(W1op, 8, kn, wv, lane);
                #pragma unroll
                for (int nt = 0; nt < 4; ++nt) {
                    f16x8 b = afrag(lds, TB, 384, nt * 16, ks * 32, lr, lg);
                    acc1o[nt][j] = MFMA16(a, b, acc1o[nt][j]);
                }
                a = nx;
            }
        }
        __syncthreads();
    }
    #pragma unroll
    for (int nt = 0; nt < 4; ++nt) {
        int node = nt * 16 + lr;
        if (node < nvalid) {
            int o0 = wv * 16 + lg * 4;
            float vals[12];
            #pragma unroll
            for (int r = 0; r < 4; ++r)
                #pragma unroll
                for (int j = 0; j < 3; ++j)
                    vals[r * 3 + j] = RS384 * acc1o[nt][j][r];
            size_t base = (size_t)(z0 + node) * 1024 + 256 + 3 * o0;
            #pragma unroll
            for (int qq = 0; qq < 3; ++qq) {
                float4 f;
                f.x = vals[qq * 4 + 0]; f.y = vals[qq * 4 + 1];
                f.z = vals[qq * 4 + 2]; f.w = vals[qq * 4 + 3];
                *(float4*)(&out[base + qq * 4]) = f;
            }
        }
    }

    // ---- P6: Mj^T = w111 @ Vj^T -> M planes; cross -> p5 planes ----
    #pragma unroll 1
    for (int j = 0; j < 3; ++j) {
        f32x4 am[4] = {};
        #pragma unroll
        for (int ks = 0; ks < 4; ++ks) {
            f16x8 a = wfrag(w111p, 8, ks, wv, lane);
            #pragma unroll
            for (int nt = 0; nt < 4; ++nt) {
                f16x8 b = afrag(lds, VBASE(j), 128, nt * 16, ks * 32, lr, lg);
                am[nt] = MFMA16(a, b, am[nt]);
            }
        }
        #pragma unroll
        for (int nt = 0; nt < 4; ++nt) {
            int node = nt * 16 + lr;
            f16x4 t4;
            #pragma unroll
            for (int r = 0; r < 4; ++r) t4[r] = (f16)am[nt][r];
            stsv4(lds, MBASE(j), 128, node, wv * 16 + lg * 4, t4);
        }
    }
    __syncthreads();
    #pragma unroll 1
    for (int q = tid; q < NT * 32; q += 512) {
        int row = q >> 5;
        int col = (q & 31) * 4;
        f16x4 v0 = ldsv4(lds, VBASE(0), 128, row, col);
        f16x4 v1 = ldsv4(lds, VBASE(1), 128, row, col);
        f16x4 v2 = ldsv4(lds, VBASE(2), 128, row, col);
        f16x4 m0 = ldsv4(lds, MBASE(0), 128, row, col);
        f16x4 m1 = ldsv4(lds, MBASE(1), 128, row, col);
        f16x4 m2 = ldsv4(lds, MBASE(2), 128, row, col);
        f16x4 c0, c1, c2;
        #pragma unroll
        for (int r = 0; r < 4; ++r) {
            c0[r] = (f16)(C111 * ((float)v1[r] * (float)m2[r] - (float)v2[r] * (float)m1[r]));
            c1[r] = (f16)(C111 * ((float)v2[r] * (float)m0[r] - (float)v0[r] * (float)m2[r]));
            c2[r] = (f16)(C111 * ((float)v0[r] * (float)m1[r] - (float)v1[r] * (float)m0[r]));
        }
        stsv4(lds, P5BASE(0), 128, row, col, c0);
        stsv4(lds, P5BASE(1), 128, row, col, c1);
        stsv4(lds, P5BASE(2), 128, row, col, c2);
    }
    __syncthreads();

    // ---- P7: out_1e^T = W1e^T @ p5^T / sqrt(128) ----
    {
        f32x4 acc[4][3] = {};
        #pragma unroll
        for (int j = 0; j < 3; ++j)
            #pragma unroll
            for (int ks = 0; ks < 4; ++ks) {
                f16x8 a = wfrag(W1ep, 8, ks, wv, lane);
                #pragma unroll
                for (int nt = 0; nt < 4; ++nt) {
                    f16x8 b = afrag(lds, P5BASE(j), 128, nt * 16, ks * 32, lr, lg);
                    acc[nt][j] = MFMA16(a, b, acc[nt][j]);
                }
            }
        #pragma unroll
        for (int nt = 0; nt < 4; ++nt) {
            int node = nt * 16 + lr;
            if (node < nvalid) {
                int o0 = wv * 16 + lg * 4;
                float vals[12];
                #pragma unroll
                for (int r = 0; r < 4; ++r)
                    #pragma unroll
                    for (int j = 0; j < 3; ++j)
                        vals[r * 3 + j] = RS128 * acc[nt][j][r];
                size_t base = (size_t)(z0 + node) * 1024 + 640 + 3 * o0;
                #pragma unroll
                for (int qq = 0; qq < 3; ++qq) {
                    float4 f;
                    f.x = vals[qq * 4 + 0]; f.y = vals[qq * 4 + 1];
                    f.z = vals[qq * 4 + 2]; f.w = vals[qq * 4 + 3];
                    *(float4*)(&out[base + qq * 4]) = f;
                }
            }
        }
    }
}

extern "C" void kernel_launch(void* const* d_in, const int* in_sizes, int n_in,
                              void* d_out, int out_size, void* d_ws, size_t ws_size,
                              hipStream_t stream) {
    const float* nf   = (const float*)d_in[0];
    const float* w00  = (const float*)d_in[1];
    const float* w01  = (const float*)d_in[2];
    const float* w10  = (const float*)d_in[3];
    const float* w110 = (const float*)d_in[4];
    const float* w111 = (const float*)d_in[5];
    const float* W0e  = (const float*)d_in[6];
    const float* W1o  = (const float*)d_in[7];
    const float* W1e  = (const float*)d_in[8];
    f16* wpack = (f16*)d_ws;  // needs 655,360 bytes

    int n_nodes = in_sizes[0] / 640;
    pack_weights<<<1280, 256, 0, stream>>>(w00, w01, w10, w110, w111, W0e, W1o, W1e, wpack);
    int blocks = (n_nodes + NT - 1) / NT;
    node_tp<<<blocks, 512, 0, stream>>>(nf, wpack, (float*)d_out, n_nodes);
}

// Round 4
// 231.148 us; speedup vs baseline: 1.1694x; 1.0261x over previous
//
#include <hip/hip_runtime.h>

typedef _Float16 f16;
typedef _Float16 f16x8 __attribute__((ext_vector_type(8)));
typedef _Float16 f16x4 __attribute__((ext_vector_type(4)));
typedef float f32x4 __attribute__((ext_vector_type(4)));

#define MFMA16(a, b, c) __builtin_amdgcn_mfma_f32_16x16x32_f16(a, b, c, 0, 0, 0)

// ---------------- weight packing (A-operand layout) ----------------
// Panels over (kb, rb); each panel = 512 f16:
//   element ((kb*(R/16)+rb)*64 + lane)*8 + i  holds  A[r][k],
//   r = rb*16 + (lane&15),  k = kb*32 + (lane>>4)*8 + i
//   A[r][k] = transpose ? W[k*R+r] : W[r*K+k]
__device__ __forceinline__ void pack_one(int local, const float* __restrict__ src,
                                         f16* __restrict__ dst, int K, int R, int transpose) {
    int i = local & 7;
    int l = (local >> 3) & 63;
    int p = local >> 9;
    int rt16 = R >> 4;
    int rb = p % rt16;
    int kb = p / rt16;
    int k = kb * 32 + ((l >> 4) << 3) + i;
    int r = rb * 16 + (l & 15);
    float v = transpose ? src[k * R + r] : src[r * K + k];
    dst[local] = (f16)v;
}

__global__ void pack_weights(const float* __restrict__ w00, const float* __restrict__ w01,
                             const float* __restrict__ w10, const float* __restrict__ w110,
                             const float* __restrict__ w111, const float* __restrict__ W0e,
                             const float* __restrict__ W1o, const float* __restrict__ W1e,
                             f16* __restrict__ dst) {
    int idx = blockIdx.x * 256 + threadIdx.x;
    // rows R = output channel dim, K = contraction dim
    if (idx < 65536)        pack_one(idx,          w00,  dst,          256, 256, 0); // A1: A[u][v]=w00[u][v]
    else if (idx < 98304)   pack_one(idx - 65536,  w01,  dst + 65536,  128, 256, 0); // A2: w01[u][v]
    else if (idx < 131072)  pack_one(idx - 98304,  w10,  dst + 98304,  256, 128, 0); // A3: w10[u][v]
    else if (idx < 147456)  pack_one(idx - 131072, w110, dst + 131072, 128, 128, 0); // A4: w110[u][v]
    else if (idx < 163840)  pack_one(idx - 147456, w111, dst + 147456, 128, 128, 0); // M : w111[u][v]
    else if (idx < 262144)  pack_one(idx - 163840, W0e,  dst + 163840, 384, 256, 1); // A[o][t]=W0e[t][o]
    else if (idx < 311296)  pack_one(idx - 262144, W1o,  dst + 262144, 384, 128, 1); // A[o][t]=W1o[t][o]
    else                    pack_one(idx - 311296, W1e,  dst + 311296, 128, 128, 1); // A[o][t]=W1e[t][o]
}

// ---------------- main fused kernel ----------------
// Transposed orientation: C[channel][node]. Weights = A-operand (global),
// node tiles = B-operand (LDS). 128-wide phases split node-tiles across
// waves (ng = wv>>2 picks 2 of 4 node-tiles, wr = wv&3 picks 2 channel
// tiles) -> per-block b128 fragment reads drop 3584 -> 2304.
#define NT 64
// LDS map (byte offsets)
#define S16B   0                        // [64][256] f16, pitch 512B
#define VBASE(j) (32768 + (j) * 16384)  // [64][128] f16, pitch 256B
#define TB     81920                    // [64][384] f16, pitch 768B
#define A3B    131072                   // [64][128] f16, pitch 256B
#define MBASE(j) (TB + (j) * 16384)     // reuse T as three [64][128] planes
#define P5BASE(j) ((j) == 0 ? A3B : (S16B + ((j) - 1) * 16384))
#define LDS_BYTES 147456

// B-operand fragment: lane holds data[row0+lr][k0 + lg*8 .. +7]
__device__ __forceinline__ f16x8 afrag(const unsigned char* lds, int base, int pitchh,
                                       int row0, int k0, int lr, int lg) {
    int row = row0 + lr;
    int off = base + row * (pitchh * 2) + (((k0 + (lg << 3)) * 2) ^ ((row & 7) << 4));
    return *(const f16x8*)(lds + off);
}
// vector (4 x f16, 8B) LDS access at (row, col), col % 4 == 0
__device__ __forceinline__ f16x4 ldsv4(const unsigned char* lds, int base, int pitchh,
                                       int row, int col) {
    int off = base + row * (pitchh * 2) + ((col * 2) ^ ((row & 7) << 4));
    return *(const f16x4*)(lds + off);
}
__device__ __forceinline__ void stsv4(unsigned char* lds, int base, int pitchh,
                                      int row, int col, f16x4 v) {
    int off = base + row * (pitchh * 2) + ((col * 2) ^ ((row & 7) << 4));
    *(f16x4*)(lds + off) = v;
}
// scalar store (P0 staging only)
__device__ __forceinline__ void ldss(unsigned char* lds, int base, int pitchh,
                                     int row, int col, float v) {
    int off = base + row * (pitchh * 2) + ((col * 2) ^ ((row & 7) << 4));
    *(f16*)(lds + off) = (f16)v;
}
// weight A-fragment from packed panel
__device__ __forceinline__ f16x8 wfrag(const f16* __restrict__ panel, int rt16, int kb,
                                       int rb, int lane) {
    return *(const f16x8*)(panel + (size_t)((kb * rt16 + rb) * 512 + lane * 8));
}

__global__ __launch_bounds__(512, 2)
void node_tp(const float* __restrict__ nf, const f16* __restrict__ wp,
             float* __restrict__ out, int n_nodes) {
    __shared__ __align__(16) unsigned char lds[LDS_BYTES];
    const int tid = threadIdx.x;
    const int lane = tid & 63;
    const int wv = tid >> 6;
    const int z0 = blockIdx.x * NT;
    const int nvalid = min(NT, n_nodes - z0);
    const int lr = lane & 15;
    const int lg = lane >> 4;
    const int ng = wv >> 2;   // node-tile group for split phases: nodes 32*ng..+31
    const int wr = wv & 3;    // channel-tile group: channels 32*wr..+31 (128-wide)

    const f16* w00p  = wp;
    const f16* w01p  = wp + 65536;
    const f16* w10p  = wp + 98304;
    const f16* w110p = wp + 131072;
    const f16* w111p = wp + 147456;
    const f16* W0ep  = wp + 163840;
    const f16* W1op  = wp + 262144;
    const f16* W1ep  = wp + 311296;

    const float C000 = 0.0625f;               // 1/sqrt(256)
    const float C011 = 0.08838834764831843f;  // 1/sqrt(128)
    const float C101 = 0.0625f;
    const float C110 = 0.05103103630798287f;  // 1/sqrt(384)
    const float C111 = 0.0625f;               // 1/16
    const float RS384 = 0.05103103630798287f;
    const float RS128 = 0.08838834764831843f;

    // ---- P0: stage node_feat -> LDS f16 (swizzled, [node][channel]) ----
    #pragma unroll 5
    for (int q = tid; q < NT * 160; q += 512) {
        int row = q / 160;
        int c4 = q - row * 160;
        float4 v4 = make_float4(0.f, 0.f, 0.f, 0.f);
        if (row < nvalid)
            v4 = ((const float4*)(nf + (size_t)(z0 + row) * 640))[c4];
        int c = c4 * 4;
        if (c < 256) {
            f16x4 h = {(f16)v4.x, (f16)v4.y, (f16)v4.z, (f16)v4.w};
            int off = S16B + row * 512 + ((c * 2) ^ ((row & 7) << 4));
            *(f16x4*)(lds + off) = h;
        } else {
            float vv[4] = {v4.x, v4.y, v4.z, v4.w};
            #pragma unroll
            for (int e = 0; e < 4; ++e) {
                int m = c - 256 + e;
                int u = m / 3;
                int j = m - u * 3;
                ldss(lds, VBASE(j), 128, row, u, vv[e]);
            }
        }
    }
    __syncthreads();

    // ---- P1: A1^T tiles = w00 @ S^T ; p1 = C000*S*A1 -> T[:,0:256] (full-nt) ----
    {
        f32x4 acc[2][4] = {};
        f16x8 a0 = wfrag(w00p, 16, 0, 2 * wv, lane);
        f16x8 a1 = wfrag(w00p, 16, 0, 2 * wv + 1, lane);
        #pragma unroll 1
        for (int ks = 0; ks < 8; ++ks) {
            int kn = ks + 1 < 8 ? ks + 1 : ks;
            f16x8 n0 = wfrag(w00p, 16, kn, 2 * wv, lane);
            f16x8 n1 = wfrag(w00p, 16, kn, 2 * wv + 1, lane);
            #pragma unroll
            for (int nt = 0; nt < 4; ++nt) {
                f16x8 b = afrag(lds, S16B, 256, nt * 16, ks * 32, lr, lg);
                acc[0][nt] = MFMA16(a0, b, acc[0][nt]);
                acc[1][nt] = MFMA16(a1, b, acc[1][nt]);
            }
            a0 = n0; a1 = n1;
        }
        #pragma unroll
        for (int rt = 0; rt < 2; ++rt)
            #pragma unroll
            for (int nt = 0; nt < 4; ++nt) {
                int node = nt * 16 + lr;
                int u0 = wv * 32 + rt * 16 + lg * 4;
                f16x4 s4 = ldsv4(lds, S16B, 256, node, u0);
                f16x4 t4;
                #pragma unroll
                for (int r = 0; r < 4; ++r)
                    t4[r] = (f16)(C000 * (float)s4[r] * acc[rt][nt][r]);
                stsv4(lds, TB, 384, node, u0, t4);
            }
    }
    // ---- P2: A4j^T = w110 @ Vj^T ; p4 = C110*sum_j Vj*A4j -> T[:,256:384] (split) ----
    {
        f32x4 acc[3][2][2] = {};
        #pragma unroll
        for (int ks = 0; ks < 4; ++ks) {
            f16x8 a0 = wfrag(w110p, 8, ks, 2 * wr, lane);
            f16x8 a1 = wfrag(w110p, 8, ks, 2 * wr + 1, lane);
            #pragma unroll
            for (int j = 0; j < 3; ++j)
                #pragma unroll
                for (int n2 = 0; n2 < 2; ++n2) {
                    f16x8 b = afrag(lds, VBASE(j), 128, (2 * ng + n2) * 16, ks * 32, lr, lg);
                    acc[j][0][n2] = MFMA16(a0, b, acc[j][0][n2]);
                    acc[j][1][n2] = MFMA16(a1, b, acc[j][1][n2]);
                }
        }
        #pragma unroll
        for (int r2 = 0; r2 < 2; ++r2)
            #pragma unroll
            for (int n2 = 0; n2 < 2; ++n2) {
                int node = (2 * ng + n2) * 16 + lr;
                int u0 = (2 * wr + r2) * 16 + lg * 4;
                float p4[4] = {0.f, 0.f, 0.f, 0.f};
                #pragma unroll
                for (int j = 0; j < 3; ++j) {
                    f16x4 v4 = ldsv4(lds, VBASE(j), 128, node, u0);
                    #pragma unroll
                    for (int r = 0; r < 4; ++r)
                        p4[r] += (float)v4[r] * acc[j][r2][n2][r];
                }
                f16x4 t4;
                #pragma unroll
                for (int r = 0; r < 4; ++r) t4[r] = (f16)(C110 * p4[r]);
                stsv4(lds, TB, 384, node, 256 + u0, t4);
            }
    }
    __syncthreads();

    // ---- P3: out_0e^T = W0e^T @ T^T / sqrt(384) (full-nt) ----
    {
        f32x4 acc[2][4] = {};
        f16x8 a0 = wfrag(W0ep, 16, 0, 2 * wv, lane);
        f16x8 a1 = wfrag(W0ep, 16, 0, 2 * wv + 1, lane);
        #pragma unroll 1
        for (int ks = 0; ks < 12; ++ks) {
            int kn = ks + 1 < 12 ? ks + 1 : ks;
            f16x8 n0 = wfrag(W0ep, 16, kn, 2 * wv, lane);
            f16x8 n1 = wfrag(W0ep, 16, kn, 2 * wv + 1, lane);
            #pragma unroll
            for (int nt = 0; nt < 4; ++nt) {
                f16x8 b = afrag(lds, TB, 384, nt * 16, ks * 32, lr, lg);
                acc[0][nt] = MFMA16(a0, b, acc[0][nt]);
                acc[1][nt] = MFMA16(a1, b, acc[1][nt]);
            }
            a0 = n0; a1 = n1;
        }
        #pragma unroll
        for (int rt = 0; rt < 2; ++rt)
            #pragma unroll
            for (int nt = 0; nt < 4; ++nt) {
                int node = nt * 16 + lr;
                if (node < nvalid) {
                    int o = wv * 32 + rt * 16 + lg * 4;
                    float4 o4;
                    o4.x = RS384 * acc[rt][nt][0];
                    o4.y = RS384 * acc[rt][nt][1];
                    o4.z = RS384 * acc[rt][nt][2];
                    o4.w = RS384 * acc[rt][nt][3];
                    *(float4*)(&out[(size_t)(z0 + node) * 1024 + o]) = o4;
                }
            }
    }
    // ---- P4: A3^T = w10 @ S^T -> A3B (split) ----
    {
        f32x4 acc[2][2] = {};
        f16x8 a0 = wfrag(w10p, 8, 0, 2 * wr, lane);
        f16x8 a1 = wfrag(w10p, 8, 0, 2 * wr + 1, lane);
        #pragma unroll 1
        for (int ks = 0; ks < 8; ++ks) {
            int kn = ks + 1 < 8 ? ks + 1 : ks;
            f16x8 n0 = wfrag(w10p, 8, kn, 2 * wr, lane);
            f16x8 n1 = wfrag(w10p, 8, kn, 2 * wr + 1, lane);
            #pragma unroll
            for (int n2 = 0; n2 < 2; ++n2) {
                f16x8 b = afrag(lds, S16B, 256, (2 * ng + n2) * 16, ks * 32, lr, lg);
                acc[0][n2] = MFMA16(a0, b, acc[0][n2]);
                acc[1][n2] = MFMA16(a1, b, acc[1][n2]);
            }
            a0 = n0; a1 = n1;
        }
        #pragma unroll
        for (int r2 = 0; r2 < 2; ++r2)
            #pragma unroll
            for (int n2 = 0; n2 < 2; ++n2) {
                int node = (2 * ng + n2) * 16 + lr;
                f16x4 t4;
                #pragma unroll
                for (int r = 0; r < 4; ++r) t4[r] = (f16)acc[r2][n2][r];
                stsv4(lds, A3B, 128, node, (2 * wr + r2) * 16 + lg * 4, t4);
            }
    }
    __syncthreads();

    // ---- P5: for j: {A2j -> p2 -> T[:,0:256]; p3 -> T[:,256:384]; out1o += W1o^T@T^T} ----
    f32x4 acc1o[2][2][3] = {};
    #pragma unroll
    for (int j = 0; j < 3; ++j) {
        {
            f32x4 a2[2][4] = {};
            #pragma unroll
            for (int ks = 0; ks < 4; ++ks) {
                f16x8 a0 = wfrag(w01p, 16, ks, 2 * wv, lane);
                f16x8 a1 = wfrag(w01p, 16, ks, 2 * wv + 1, lane);
                #pragma unroll
                for (int nt = 0; nt < 4; ++nt) {
                    f16x8 b = afrag(lds, VBASE(j), 128, nt * 16, ks * 32, lr, lg);
                    a2[0][nt] = MFMA16(a0, b, a2[0][nt]);
                    a2[1][nt] = MFMA16(a1, b, a2[1][nt]);
                }
            }
            #pragma unroll
            for (int rt = 0; rt < 2; ++rt)
                #pragma unroll
                for (int nt = 0; nt < 4; ++nt) {
                    int node = nt * 16 + lr;
                    int u0 = wv * 32 + rt * 16 + lg * 4;
                    f16x4 s4 = ldsv4(lds, S16B, 256, node, u0);
                    f16x4 t4;
                    #pragma unroll
                    for (int r = 0; r < 4; ++r)
                        t4[r] = (f16)(C011 * (float)s4[r] * a2[rt][nt][r]);
                    stsv4(lds, TB, 384, node, u0, t4);
                }
        }
        #pragma unroll 1
        for (int q = tid; q < NT * 32; q += 512) {
            int row = q >> 5;
            int col = (q & 31) * 4;
            f16x4 v4 = ldsv4(lds, VBASE(j), 128, row, col);
            f16x4 a34 = ldsv4(lds, A3B, 128, row, col);
            f16x4 t4;
            #pragma unroll
            for (int r = 0; r < 4; ++r)
                t4[r] = (f16)(C101 * (float)v4[r] * (float)a34[r]);
            stsv4(lds, TB, 384, row, 256 + col, t4);
        }
        __syncthreads();
        {
            f16x8 a0 = wfrag(W1op, 8, 0, 2 * wr, lane);
            f16x8 a1 = wfrag(W1op, 8, 0, 2 * wr + 1, lane);
            #pragma unroll 1
            for (int ks = 0; ks < 12; ++ks) {
                int kn = ks + 1 < 12 ? ks + 1 : ks;
                f16x8 n0 = wfrag(W1op, 8, kn, 2 * wr, lane);
                f16x8 n1 = wfrag(W1op, 8, kn, 2 * wr + 1, lane);
                #pragma unroll
                for (int n2 = 0; n2 < 2; ++n2) {
                    f16x8 b = afrag(lds, TB, 384, (2 * ng + n2) * 16, ks * 32, lr, lg);
                    acc1o[0][n2][j] = MFMA16(a0, b, acc1o[0][n2][j]);
                    acc1o[1][n2][j] = MFMA16(a1, b, acc1o[1][n2][j]);
                }
                a0 = n0; a1 = n1;
            }
        }
        __syncthreads();
    }
    #pragma unroll
    for (int r2 = 0; r2 < 2; ++r2)
        #pragma unroll
        for (int n2 = 0; n2 < 2; ++n2) {
            int node = (2 * ng + n2) * 16 + lr;
            if (node < nvalid) {
                int o0 = (2 * wr + r2) * 16 + lg * 4;
                float vals[12];
                #pragma unroll
                for (int r = 0; r < 4; ++r)
                    #pragma unroll
                    for (int j = 0; j < 3; ++j)
                        vals[r * 3 + j] = RS384 * acc1o[r2][n2][j][r];
                size_t base = (size_t)(z0 + node) * 1024 + 256 + 3 * o0;
                #pragma unroll
                for (int qq = 0; qq < 3; ++qq) {
                    float4 f;
                    f.x = vals[qq * 4 + 0]; f.y = vals[qq * 4 + 1];
                    f.z = vals[qq * 4 + 2]; f.w = vals[qq * 4 + 3];
                    *(float4*)(&out[base + qq * 4]) = f;
                }
            }
        }

    // ---- P6: Mj^T = w111 @ Vj^T -> M planes (split); cross -> p5 planes ----
    #pragma unroll 1
    for (int j = 0; j < 3; ++j) {
        f32x4 am[2][2] = {};
        #pragma unroll
        for (int ks = 0; ks < 4; ++ks) {
            f16x8 a0 = wfrag(w111p, 8, ks, 2 * wr, lane);
            f16x8 a1 = wfrag(w111p, 8, ks, 2 * wr + 1, lane);
            #pragma unroll
            for (int n2 = 0; n2 < 2; ++n2) {
                f16x8 b = afrag(lds, VBASE(j), 128, (2 * ng + n2) * 16, ks * 32, lr, lg);
                am[0][n2] = MFMA16(a0, b, am[0][n2]);
                am[1][n2] = MFMA16(a1, b, am[1][n2]);
            }
        }
        #pragma unroll
        for (int r2 = 0; r2 < 2; ++r2)
            #pragma unroll
            for (int n2 = 0; n2 < 2; ++n2) {
                int node = (2 * ng + n2) * 16 + lr;
                f16x4 t4;
                #pragma unroll
                for (int r = 0; r < 4; ++r) t4[r] = (f16)am[r2][n2][r];
                stsv4(lds, MBASE(j), 128, node, (2 * wr + r2) * 16 + lg * 4, t4);
            }
    }
    __syncthreads();
    #pragma unroll 1
    for (int q = tid; q < NT * 32; q += 512) {
        int row = q >> 5;
        int col = (q & 31) * 4;
        f16x4 v0 = ldsv4(lds, VBASE(0), 128, row, col);
        f16x4 v1 = ldsv4(lds, VBASE(1), 128, row, col);
        f16x4 v2 = ldsv4(lds, VBASE(2), 128, row, col);
        f16x4 m0 = ldsv4(lds, MBASE(0), 128, row, col);
        f16x4 m1 = ldsv4(lds, MBASE(1), 128, row, col);
        f16x4 m2 = ldsv4(lds, MBASE(2), 128, row, col);
        f16x4 c0, c1, c2;
        #pragma unroll
        for (int r = 0; r < 4; ++r) {
            c0[r] = (f16)(C111 * ((float)v1[r] * (float)m2[r] - (float)v2[r] * (float)m1[r]));
            c1[r] = (f16)(C111 * ((float)v2[r] * (float)m0[r] - (float)v0[r] * (float)m2[r]));
            c2[r] = (f16)(C111 * ((float)v0[r] * (float)m1[r] - (float)v1[r] * (float)m0[r]));
        }
        stsv4(lds, P5BASE(0), 128, row, col, c0);
        stsv4(lds, P5BASE(1), 128, row, col, c1);
        stsv4(lds, P5BASE(2), 128, row, col, c2);
    }
    __syncthreads();

    // ---- P7: out_1e^T = W1e^T @ p5^T / sqrt(128) (split) ----
    {
        f32x4 acc[2][2][3] = {};
        #pragma unroll
        for (int j = 0; j < 3; ++j)
            #pragma unroll
            for (int ks = 0; ks < 4; ++ks) {
                f16x8 a0 = wfrag(W1ep, 8, ks, 2 * wr, lane);
                f16x8 a1 = wfrag(W1ep, 8, ks, 2 * wr + 1, lane);
                #pragma unroll
                for (int n2 = 0; n2 < 2; ++n2) {
                    f16x8 b = afrag(lds, P5BASE(j), 128, (2 * ng + n2) * 16, ks * 32, lr, lg);
                    acc[0][n2][j] = MFMA16(a0, b, acc[0][n2][j]);
                    acc[1][n2][j] = MFMA16(a1, b, acc[1][n2][j]);
                }
            }
        #pragma unroll
        for (int r2 = 0; r2 < 2; ++r2)
            #pragma unroll
            for (int n2 = 0; n2 < 2; ++n2) {
                int node = (2 * ng + n2) * 16 + lr;
                if (node < nvalid) {
                    int o0 = (2 * wr + r2) * 16 + lg * 4;
                    float vals[12];
                    #pragma unroll
                    for (int r = 0; r < 4; ++r)
                        #pragma unroll
                        for (int j = 0; j < 3; ++j)
                            vals[r * 3 + j] = RS128 * acc[r2][n2][j][r];
                    size_t base = (size_t)(z0 + node) * 1024 + 640 + 3 * o0;
                    #pragma unroll
                    for (int qq = 0; qq < 3; ++qq) {
                        float4 f;
                        f.x = vals[qq * 4 + 0]; f.y = vals[qq * 4 + 1];
                        f.z = vals[qq * 4 + 2]; f.w = vals[qq * 4 + 3];
                        *(float4*)(&out[base + qq * 4]) = f;
                    }
                }
            }
    }
}

extern "C" void kernel_launch(void* const* d_in, const int* in_sizes, int n_in,
                              void* d_out, int out_size, void* d_ws, size_t ws_size,
                              hipStream_t stream) {
    const float* nf   = (const float*)d_in[0];
    const float* w00  = (const float*)d_in[1];
    const float* w01  = (const float*)d_in[2];
    const float* w10  = (const float*)d_in[3];
    const float* w110 = (const float*)d_in[4];
    const float* w111 = (const float*)d_in[5];
    const float* W0e  = (const float*)d_in[6];
    const float* W1o  = (const float*)d_in[7];
    const float* W1e  = (const float*)d_in[8];
    f16* wpack = (f16*)d_ws;  // needs 655,360 bytes

    int n_nodes = in_sizes[0] / 640;
    pack_weights<<<1280, 256, 0, stream>>>(w00, w01, w10, w110, w111, W0e, W1o, W1e, wpack);
    int blocks = (n_nodes + NT - 1) / NT;
    node_tp<<<blocks, 512, 0, stream>>>(nf, wpack, (float*)d_out, n_nodes);
}

// Round 5
// 194.202 us; speedup vs baseline: 1.3918x; 1.1902x over previous
//
#include <hip/hip_runtime.h>

typedef _Float16 f16;
typedef _Float16 f16x8 __attribute__((ext_vector_type(8)));
typedef _Float16 f16x4 __attribute__((ext_vector_type(4)));
typedef float f32x4 __attribute__((ext_vector_type(4)));

#define MFMA16(a, b, c) __builtin_amdgcn_mfma_f32_16x16x32_f16(a, b, c, 0, 0, 0)

// ---------------- weight packing (A-operand layout) ----------------
// Panels over (kb, rb); each panel = 512 f16:
//   element ((kb*(R/16)+rb)*64 + lane)*8 + i  holds  A[r][k],
//   r = rb*16 + (lane&15),  k = kb*32 + (lane>>4)*8 + i
//   A[r][k] = transpose ? W[k*R+r] : W[r*K+k]
__device__ __forceinline__ void pack_one(int local, const float* __restrict__ src,
                                         f16* __restrict__ dst, int K, int R, int transpose) {
    int i = local & 7;
    int l = (local >> 3) & 63;
    int p = local >> 9;
    int rt16 = R >> 4;
    int rb = p % rt16;
    int kb = p / rt16;
    int k = kb * 32 + ((l >> 4) << 3) + i;
    int r = rb * 16 + (l & 15);
    float v = transpose ? src[k * R + r] : src[r * K + k];
    dst[local] = (f16)v;
}

__global__ void pack_weights(const float* __restrict__ w00, const float* __restrict__ w01,
                             const float* __restrict__ w10, const float* __restrict__ w110,
                             const float* __restrict__ w111, const float* __restrict__ W0e,
                             const float* __restrict__ W1o, const float* __restrict__ W1e,
                             f16* __restrict__ dst) {
    int idx = blockIdx.x * 256 + threadIdx.x;
    // rows R = output channel dim, K = contraction dim
    if (idx < 65536)        pack_one(idx,          w00,  dst,          256, 256, 0); // A1: A[u][v]=w00[u][v]
    else if (idx < 98304)   pack_one(idx - 65536,  w01,  dst + 65536,  128, 256, 0); // A2: w01[u][v]
    else if (idx < 131072)  pack_one(idx - 98304,  w10,  dst + 98304,  256, 128, 0); // A3: w10[u][v]
    else if (idx < 147456)  pack_one(idx - 131072, w110, dst + 131072, 128, 128, 0); // A4: w110[u][v]
    else if (idx < 163840)  pack_one(idx - 147456, w111, dst + 147456, 128, 128, 0); // M : w111[u][v]
    else if (idx < 262144)  pack_one(idx - 163840, W0e,  dst + 163840, 384, 256, 1); // A[o][t]=W0e[t][o]
    else if (idx < 311296)  pack_one(idx - 262144, W1o,  dst + 262144, 384, 128, 1); // A[o][t]=W1o[t][o]
    else                    pack_one(idx - 311296, W1e,  dst + 311296, 128, 128, 1); // A[o][t]=W1e[t][o]
}

// ---------------- main fused kernel ----------------
// NT=32, LDS 72 KiB -> 2 blocks/CU with __launch_bounds__(512,2) (natural
// VGPR ~80 <= 128 -> 4 waves/SIMD; round-1's spill trap was the forced
// (512,4) bound). Two co-resident blocks overlap barrier/latency stalls
// and de-quantize the 3.05-round tail. Transposed orientation kept:
// C[channel][node], weights = A-operand, node tiles = B-operand in LDS.
#define NT 32
// LDS map (byte offsets)
#define S16B   0                        // [32][256] f16, pitch 512B (16 KiB)
#define VBASE(j) (16384 + (j) * 8192)   // [32][128] f16, pitch 256B (3 x 8 KiB)
#define TB     40960                    // [32][384] f16, pitch 768B (24 KiB)
#define A3B    65536                    // [32][128] f16, pitch 256B (8 KiB)
#define MBASE(j) (TB + (j) * 8192)      // reuse T as three [32][128] planes
#define P5BASE(j) ((j) == 0 ? A3B : (S16B + ((j) - 1) * 8192))
#define LDS_BYTES 73728

// B-operand fragment: lane holds data[row0+lr][k0 + lg*8 .. +7]
__device__ __forceinline__ f16x8 afrag(const unsigned char* lds, int base, int pitchh,
                                       int row0, int k0, int lr, int lg) {
    int row = row0 + lr;
    int off = base + row * (pitchh * 2) + (((k0 + (lg << 3)) * 2) ^ ((row & 7) << 4));
    return *(const f16x8*)(lds + off);
}
// vector (4 x f16, 8B) LDS access at (row, col), col % 4 == 0
__device__ __forceinline__ f16x4 ldsv4(const unsigned char* lds, int base, int pitchh,
                                       int row, int col) {
    int off = base + row * (pitchh * 2) + ((col * 2) ^ ((row & 7) << 4));
    return *(const f16x4*)(lds + off);
}
__device__ __forceinline__ void stsv4(unsigned char* lds, int base, int pitchh,
                                      int row, int col, f16x4 v) {
    int off = base + row * (pitchh * 2) + ((col * 2) ^ ((row & 7) << 4));
    *(f16x4*)(lds + off) = v;
}
// scalar store (P0 staging only)
__device__ __forceinline__ void ldss(unsigned char* lds, int base, int pitchh,
                                     int row, int col, float v) {
    int off = base + row * (pitchh * 2) + ((col * 2) ^ ((row & 7) << 4));
    *(f16*)(lds + off) = (f16)v;
}
// weight A-fragment from packed panel
__device__ __forceinline__ f16x8 wfrag(const f16* __restrict__ panel, int rt16, int kb,
                                       int rb, int lane) {
    return *(const f16x8*)(panel + (size_t)((kb * rt16 + rb) * 512 + lane * 8));
}

__global__ __launch_bounds__(512, 2)
void node_tp(const float* __restrict__ nf, const f16* __restrict__ wp,
             float* __restrict__ out, int n_nodes) {
    __shared__ __align__(16) unsigned char lds[LDS_BYTES];
    const int tid = threadIdx.x;
    const int lane = tid & 63;
    const int wv = tid >> 6;
    const int z0 = blockIdx.x * NT;
    const int nvalid = min(NT, n_nodes - z0);
    const int lr = lane & 15;
    const int lg = lane >> 4;
    const int ng = wv >> 2;   // node-tile (of 2) for split phases
    const int wr = wv & 3;    // channel-tile pair for split phases (128-wide)

    const f16* w00p  = wp;
    const f16* w01p  = wp + 65536;
    const f16* w10p  = wp + 98304;
    const f16* w110p = wp + 131072;
    const f16* w111p = wp + 147456;
    const f16* W0ep  = wp + 163840;
    const f16* W1op  = wp + 262144;
    const f16* W1ep  = wp + 311296;

    const float C000 = 0.0625f;               // 1/sqrt(256)
    const float C011 = 0.08838834764831843f;  // 1/sqrt(128)
    const float C101 = 0.0625f;
    const float C110 = 0.05103103630798287f;  // 1/sqrt(384)
    const float C111 = 0.0625f;               // 1/16
    const float RS384 = 0.05103103630798287f;
    const float RS128 = 0.08838834764831843f;

    // ---- P0: stage node_feat -> LDS f16 (swizzled, [node][channel]) ----
    #pragma unroll 5
    for (int q = tid; q < NT * 160; q += 512) {
        int row = q / 160;
        int c4 = q - row * 160;
        float4 v4 = make_float4(0.f, 0.f, 0.f, 0.f);
        if (row < nvalid)
            v4 = ((const float4*)(nf + (size_t)(z0 + row) * 640))[c4];
        int c = c4 * 4;
        if (c < 256) {
            f16x4 h = {(f16)v4.x, (f16)v4.y, (f16)v4.z, (f16)v4.w};
            int off = S16B + row * 512 + ((c * 2) ^ ((row & 7) << 4));
            *(f16x4*)(lds + off) = h;
        } else {
            float vv[4] = {v4.x, v4.y, v4.z, v4.w};
            #pragma unroll
            for (int e = 0; e < 4; ++e) {
                int m = c - 256 + e;
                int u = m / 3;
                int j = m - u * 3;
                ldss(lds, VBASE(j), 128, row, u, vv[e]);
            }
        }
    }
    __syncthreads();

    // ---- P1: A1^T = w00 @ S^T ; p1 = C000*S*A1 -> T[:,0:256] (full-nt) ----
    {
        f32x4 acc[2][2] = {};
        f16x8 a0 = wfrag(w00p, 16, 0, 2 * wv, lane);
        f16x8 a1 = wfrag(w00p, 16, 0, 2 * wv + 1, lane);
        #pragma unroll 1
        for (int ks = 0; ks < 8; ++ks) {
            int kn = ks + 1 < 8 ? ks + 1 : ks;
            f16x8 n0 = wfrag(w00p, 16, kn, 2 * wv, lane);
            f16x8 n1 = wfrag(w00p, 16, kn, 2 * wv + 1, lane);
            #pragma unroll
            for (int nt = 0; nt < 2; ++nt) {
                f16x8 b = afrag(lds, S16B, 256, nt * 16, ks * 32, lr, lg);
                acc[0][nt] = MFMA16(a0, b, acc[0][nt]);
                acc[1][nt] = MFMA16(a1, b, acc[1][nt]);
            }
            a0 = n0; a1 = n1;
        }
        #pragma unroll
        for (int rt = 0; rt < 2; ++rt)
            #pragma unroll
            for (int nt = 0; nt < 2; ++nt) {
                int node = nt * 16 + lr;
                int u0 = wv * 32 + rt * 16 + lg * 4;
                f16x4 s4 = ldsv4(lds, S16B, 256, node, u0);
                f16x4 t4;
                #pragma unroll
                for (int r = 0; r < 4; ++r)
                    t4[r] = (f16)(C000 * (float)s4[r] * acc[rt][nt][r]);
                stsv4(lds, TB, 384, node, u0, t4);
            }
    }
    // ---- P2: A4j^T = w110 @ Vj^T ; p4 = C110*sum_j Vj*A4j -> T[:,256:384] (split) ----
    {
        f32x4 acc[3][2] = {};  // [j][r2]
        #pragma unroll
        for (int ks = 0; ks < 4; ++ks) {
            f16x8 a0 = wfrag(w110p, 8, ks, 2 * wr, lane);
            f16x8 a1 = wfrag(w110p, 8, ks, 2 * wr + 1, lane);
            #pragma unroll
            for (int j = 0; j < 3; ++j) {
                f16x8 b = afrag(lds, VBASE(j), 128, ng * 16, ks * 32, lr, lg);
                acc[j][0] = MFMA16(a0, b, acc[j][0]);
                acc[j][1] = MFMA16(a1, b, acc[j][1]);
            }
        }
        #pragma unroll
        for (int r2 = 0; r2 < 2; ++r2) {
            int node = ng * 16 + lr;
            int u0 = (2 * wr + r2) * 16 + lg * 4;
            float p4[4] = {0.f, 0.f, 0.f, 0.f};
            #pragma unroll
            for (int j = 0; j < 3; ++j) {
                f16x4 v4 = ldsv4(lds, VBASE(j), 128, node, u0);
                #pragma unroll
                for (int r = 0; r < 4; ++r)
                    p4[r] += (float)v4[r] * acc[j][r2][r];
            }
            f16x4 t4;
            #pragma unroll
            for (int r = 0; r < 4; ++r) t4[r] = (f16)(C110 * p4[r]);
            stsv4(lds, TB, 384, node, 256 + u0, t4);
        }
    }
    __syncthreads();

    // ---- P3: out_0e^T = W0e^T @ T^T / sqrt(384) (full-nt) ----
    {
        f32x4 acc[2][2] = {};
        f16x8 a0 = wfrag(W0ep, 16, 0, 2 * wv, lane);
        f16x8 a1 = wfrag(W0ep, 16, 0, 2 * wv + 1, lane);
        #pragma unroll 1
        for (int ks = 0; ks < 12; ++ks) {
            int kn = ks + 1 < 12 ? ks + 1 : ks;
            f16x8 n0 = wfrag(W0ep, 16, kn, 2 * wv, lane);
            f16x8 n1 = wfrag(W0ep, 16, kn, 2 * wv + 1, lane);
            #pragma unroll
            for (int nt = 0; nt < 2; ++nt) {
                f16x8 b = afrag(lds, TB, 384, nt * 16, ks * 32, lr, lg);
                acc[0][nt] = MFMA16(a0, b, acc[0][nt]);
                acc[1][nt] = MFMA16(a1, b, acc[1][nt]);
            }
            a0 = n0; a1 = n1;
        }
        #pragma unroll
        for (int rt = 0; rt < 2; ++rt)
            #pragma unroll
            for (int nt = 0; nt < 2; ++nt) {
                int node = nt * 16 + lr;
                if (node < nvalid) {
                    int o = wv * 32 + rt * 16 + lg * 4;
                    float4 o4;
                    o4.x = RS384 * acc[rt][nt][0];
                    o4.y = RS384 * acc[rt][nt][1];
                    o4.z = RS384 * acc[rt][nt][2];
                    o4.w = RS384 * acc[rt][nt][3];
                    *(float4*)(&out[(size_t)(z0 + node) * 1024 + o]) = o4;
                }
            }
    }
    // ---- P4: A3^T = w10 @ S^T -> A3B (split) ----
    {
        f32x4 acc[2] = {};
        f16x8 a0 = wfrag(w10p, 8, 0, 2 * wr, lane);
        f16x8 a1 = wfrag(w10p, 8, 0, 2 * wr + 1, lane);
        #pragma unroll 1
        for (int ks = 0; ks < 8; ++ks) {
            int kn = ks + 1 < 8 ? ks + 1 : ks;
            f16x8 n0 = wfrag(w10p, 8, kn, 2 * wr, lane);
            f16x8 n1 = wfrag(w10p, 8, kn, 2 * wr + 1, lane);
            f16x8 b = afrag(lds, S16B, 256, ng * 16, ks * 32, lr, lg);
            acc[0] = MFMA16(a0, b, acc[0]);
            acc[1] = MFMA16(a1, b, acc[1]);
            a0 = n0; a1 = n1;
        }
        #pragma unroll
        for (int r2 = 0; r2 < 2; ++r2) {
            int node = ng * 16 + lr;
            f16x4 t4;
            #pragma unroll
            for (int r = 0; r < 4; ++r) t4[r] = (f16)acc[r2][r];
            stsv4(lds, A3B, 128, node, (2 * wr + r2) * 16 + lg * 4, t4);
        }
    }
    __syncthreads();

    // ---- P5: for j: {A2j -> p2 -> T[:,0:256]; p3 -> T[:,256:384]; out1o += W1o^T@T^T} ----
    f32x4 acc1o[2][3] = {};  // [r2][j]
    #pragma unroll
    for (int j = 0; j < 3; ++j) {
        {
            f32x4 a2[2][2] = {};
            #pragma unroll
            for (int ks = 0; ks < 4; ++ks) {
                f16x8 a0 = wfrag(w01p, 16, ks, 2 * wv, lane);
                f16x8 a1 = wfrag(w01p, 16, ks, 2 * wv + 1, lane);
                #pragma unroll
                for (int nt = 0; nt < 2; ++nt) {
                    f16x8 b = afrag(lds, VBASE(j), 128, nt * 16, ks * 32, lr, lg);
                    a2[0][nt] = MFMA16(a0, b, a2[0][nt]);
                    a2[1][nt] = MFMA16(a1, b, a2[1][nt]);
                }
            }
            #pragma unroll
            for (int rt = 0; rt < 2; ++rt)
                #pragma unroll
                for (int nt = 0; nt < 2; ++nt) {
                    int node = nt * 16 + lr;
                    int u0 = wv * 32 + rt * 16 + lg * 4;
                    f16x4 s4 = ldsv4(lds, S16B, 256, node, u0);
                    f16x4 t4;
                    #pragma unroll
                    for (int r = 0; r < 4; ++r)
                        t4[r] = (f16)(C011 * (float)s4[r] * a2[rt][nt][r]);
                    stsv4(lds, TB, 384, node, u0, t4);
                }
        }
        #pragma unroll 1
        for (int q = tid; q < NT * 32; q += 512) {
            int row = q >> 5;
            int col = (q & 31) * 4;
            f16x4 v4 = ldsv4(lds, VBASE(j), 128, row, col);
            f16x4 a34 = ldsv4(lds, A3B, 128, row, col);
            f16x4 t4;
            #pragma unroll
            for (int r = 0; r < 4; ++r)
                t4[r] = (f16)(C101 * (float)v4[r] * (float)a34[r]);
            stsv4(lds, TB, 384, row, 256 + col, t4);
        }
        __syncthreads();
        {
            f16x8 a0 = wfrag(W1op, 8, 0, 2 * wr, lane);
            f16x8 a1 = wfrag(W1op, 8, 0, 2 * wr + 1, lane);
            #pragma unroll 1
            for (int ks = 0; ks < 12; ++ks) {
                int kn = ks + 1 < 12 ? ks + 1 : ks;
                f16x8 n0 = wfrag(W1op, 8, kn, 2 * wr, lane);
                f16x8 n1 = wfrag(W1op, 8, kn, 2 * wr + 1, lane);
                f16x8 b = afrag(lds, TB, 384, ng * 16, ks * 32, lr, lg);
                acc1o[0][j] = MFMA16(a0, b, acc1o[0][j]);
                acc1o[1][j] = MFMA16(a1, b, acc1o[1][j]);
                a0 = n0; a1 = n1;
            }
        }
        __syncthreads();
    }
    #pragma unroll
    for (int r2 = 0; r2 < 2; ++r2) {
        int node = ng * 16 + lr;
        if (node < nvalid) {
            int o0 = (2 * wr + r2) * 16 + lg * 4;
            float vals[12];
            #pragma unroll
            for (int r = 0; r < 4; ++r)
                #pragma unroll
                for (int j = 0; j < 3; ++j)
                    vals[r * 3 + j] = RS384 * acc1o[r2][j][r];
            size_t base = (size_t)(z0 + node) * 1024 + 256 + 3 * o0;
            #pragma unroll
            for (int qq = 0; qq < 3; ++qq) {
                float4 f;
                f.x = vals[qq * 4 + 0]; f.y = vals[qq * 4 + 1];
                f.z = vals[qq * 4 + 2]; f.w = vals[qq * 4 + 3];
                *(float4*)(&out[base + qq * 4]) = f;
            }
        }
    }

    // ---- P6: Mj^T = w111 @ Vj^T -> M planes (split); cross -> p5 planes ----
    #pragma unroll 1
    for (int j = 0; j < 3; ++j) {
        f32x4 am[2] = {};
        #pragma unroll
        for (int ks = 0; ks < 4; ++ks) {
            f16x8 a0 = wfrag(w111p, 8, ks, 2 * wr, lane);
            f16x8 a1 = wfrag(w111p, 8, ks, 2 * wr + 1, lane);
            f16x8 b = afrag(lds, VBASE(j), 128, ng * 16, ks * 32, lr, lg);
            am[0] = MFMA16(a0, b, am[0]);
            am[1] = MFMA16(a1, b, am[1]);
        }
        #pragma unroll
        for (int r2 = 0; r2 < 2; ++r2) {
            int node = ng * 16 + lr;
            f16x4 t4;
            #pragma unroll
            for (int r = 0; r < 4; ++r) t4[r] = (f16)am[r2][r];
            stsv4(lds, MBASE(j), 128, node, (2 * wr + r2) * 16 + lg * 4, t4);
        }
    }
    __syncthreads();
    #pragma unroll 1
    for (int q = tid; q < NT * 32; q += 512) {
        int row = q >> 5;
        int col = (q & 31) * 4;
        f16x4 v0 = ldsv4(lds, VBASE(0), 128, row, col);
        f16x4 v1 = ldsv4(lds, VBASE(1), 128, row, col);
        f16x4 v2 = ldsv4(lds, VBASE(2), 128, row, col);
        f16x4 m0 = ldsv4(lds, MBASE(0), 128, row, col);
        f16x4 m1 = ldsv4(lds, MBASE(1), 128, row, col);
        f16x4 m2 = ldsv4(lds, MBASE(2), 128, row, col);
        f16x4 c0, c1, c2;
        #pragma unroll
        for (int r = 0; r < 4; ++r) {
            c0[r] = (f16)(C111 * ((float)v1[r] * (float)m2[r] - (float)v2[r] * (float)m1[r]));
            c1[r] = (f16)(C111 * ((float)v2[r] * (float)m0[r] - (float)v0[r] * (float)m2[r]));
            c2[r] = (f16)(C111 * ((float)v0[r] * (float)m1[r] - (float)v1[r] * (float)m0[r]));
        }
        stsv4(lds, P5BASE(0), 128, row, col, c0);
        stsv4(lds, P5BASE(1), 128, row, col, c1);
        stsv4(lds, P5BASE(2), 128, row, col, c2);
    }
    __syncthreads();

    // ---- P7: out_1e^T = W1e^T @ p5^T / sqrt(128) (split) ----
    {
        f32x4 acc[2][3] = {};  // [r2][j]
        #pragma unroll
        for (int j = 0; j < 3; ++j)
            #pragma unroll
            for (int ks = 0; ks < 4; ++ks) {
                f16x8 a0 = wfrag(W1ep, 8, ks, 2 * wr, lane);
                f16x8 a1 = wfrag(W1ep, 8, ks, 2 * wr + 1, lane);
                f16x8 b = afrag(lds, P5BASE(j), 128, ng * 16, ks * 32, lr, lg);
                acc[0][j] = MFMA16(a0, b, acc[0][j]);
                acc[1][j] = MFMA16(a1, b, acc[1][j]);
            }
        #pragma unroll
        for (int r2 = 0; r2 < 2; ++r2) {
            int node = ng * 16 + lr;
            if (node < nvalid) {
                int o0 = (2 * wr + r2) * 16 + lg * 4;
                float vals[12];
                #pragma unroll
                for (int r = 0; r < 4; ++r)
                    #pragma unroll
                    for (int j = 0; j < 3; ++j)
                        vals[r * 3 + j] = RS128 * acc[r2][j][r];
                size_t base = (size_t)(z0 + node) * 1024 + 640 + 3 * o0;
                #pragma unroll
                for (int qq = 0; qq < 3; ++qq) {
                    float4 f;
                    f.x = vals[qq * 4 + 0]; f.y = vals[qq * 4 + 1];
                    f.z = vals[qq * 4 + 2]; f.w = vals[qq * 4 + 3];
                    *(float4*)(&out[base + qq * 4]) = f;
                }
            }
        }
    }
}

extern "C" void kernel_launch(void* const* d_in, const int* in_sizes, int n_in,
                              void* d_out, int out_size, void* d_ws, size_t ws_size,
                              hipStream_t stream) {
    const float* nf   = (const float*)d_in[0];
    const float* w00  = (const float*)d_in[1];
    const float* w01  = (const float*)d_in[2];
    const float* w10  = (const float*)d_in[3];
    const float* w110 = (const float*)d_in[4];
    const float* w111 = (const float*)d_in[5];
    const float* W0e  = (const float*)d_in[6];
    const float* W1o  = (const float*)d_in[7];
    const float* W1e  = (const float*)d_in[8];
    f16* wpack = (f16*)d_ws;  // needs 655,360 bytes

    int n_nodes = in_sizes[0] / 640;
    pack_weights<<<1280, 256, 0, stream>>>(w00, w01, w10, w110, w111, W0e, W1o, W1e, wpack);
    int blocks = (n_nodes + NT - 1) / NT;
    node_tp<<<blocks, 512, 0, stream>>>(nf, wpack, (float*)d_out, n_nodes);
}